// Round 1
// baseline (645.097 us; speedup 1.0000x reference)
//
#include <hip/hip_runtime.h>
#include <hip/hip_bf16.h>

// SchNet forward on MI355X.
// Strategy: W(d) depends only on scalar d -> precompute 4096x128 lookup table
// (linear interp, rel err ~3e-5), ELL bucketing by destination row to make
// segment_sum atomic-free, fp32 register-tiled GEMMs for the 128x128 mixes.

#define NN 50000      // nodes
#define NE 800000     // edges
#define NGR 512       // graphs
#define HD 128        // hidden
#define FD 128        // filters
#define GG 50         // gaussians
#define NB 4096       // table bins
#define DMAXT 12.0f   // table covers [0,12]; beyond, W is constant (gauss < e^-48)
#define ELLS 80       // ELL stride; deg ~ Poisson(16), P(deg>80) ~ 0

#define DELTA (10.0f/49.0f)
#define COEFF (-0.5f/(DELTA*DELTA))

static __device__ __forceinline__ float sspf(float x) {
    // softplus(x) - log(2), numerically stable
    return fmaxf(x, 0.0f) + log1pf(expf(-fabsf(x))) - 0.69314718055994531f;
}

// h[i,:] = emb[charges[i],:]  (float4-vectorized)
__global__ __launch_bounds__(256) void k_embed(const int* __restrict__ charges,
                                               const float* __restrict__ emb,
                                               float* __restrict__ h) {
    int idx = blockIdx.x * blockDim.x + threadIdx.x;   // over NN*32 float4s
    if (idx >= NN * (HD / 4)) return;
    int i  = idx >> 5;          // node
    int f4 = idx & 31;          // float4 within row
    ((float4*)h)[idx] = ((const float4*)emb)[charges[i] * (HD / 4) + f4];
}

// Build table T[b,:] = ssp(gauss(d_b)@w_e1 + b_e1)@w_e2 + b_e2,  d_b = b*DMAXT/(NB-1)
__global__ __launch_bounds__(128) void k_table(const float* __restrict__ w_e1,
                                               const float* __restrict__ b_e1,
                                               const float* __restrict__ w_e2,
                                               const float* __restrict__ b_e2,
                                               float* __restrict__ T) {
    __shared__ float a[GG];
    __shared__ float y[FD];
    int b = blockIdx.x;
    int f = threadIdx.x;          // 0..127
    float d = (float)b * (DMAXT / (float)(NB - 1));
    if (f < GG) {
        float off = (float)f * DELTA;
        float t = d - off;
        a[f] = expf(COEFF * t * t);
    }
    __syncthreads();
    float acc = b_e1[f];
    #pragma unroll 10
    for (int g = 0; g < GG; ++g) acc = fmaf(a[g], w_e1[g * FD + f], acc);
    y[f] = sspf(acc);
    __syncthreads();
    float acc2 = b_e2[f];
    #pragma unroll 8
    for (int k = 0; k < FD; ++k) acc2 = fmaf(y[k], w_e2[k * FD + f], acc2);
    T[b * FD + f] = acc2;
}

// Per edge: d = |coords[row]-coords[col]|; bucket (col, d) into ELL slot of row.
__global__ __launch_bounds__(256) void k_edgeprep(const int* __restrict__ eidx,
                                                  const float* __restrict__ coords,
                                                  int* __restrict__ deg,
                                                  int* __restrict__ ecol,
                                                  float* __restrict__ ed) {
    int e = blockIdx.x * blockDim.x + threadIdx.x;
    if (e >= NE) return;
    int r = eidx[e];
    int c = eidx[NE + e];
    float dx = coords[r * 3 + 0] - coords[c * 3 + 0];
    float dy = coords[r * 3 + 1] - coords[c * 3 + 1];
    float dz = coords[r * 3 + 2] - coords[c * 3 + 2];
    float d = sqrtf(dx * dx + dy * dy + dz * dz);
    int pos = atomicAdd(&deg[r], 1);
    if (pos < ELLS) {
        ecol[r * ELLS + pos] = c;
        ed[r * ELLS + pos] = d;
    }
}

// Cout[M,128] = A[M,128] @ B[128,128] (+ Cin) (+ bias).  64-row tiles, kc=64 slabs.
// 256 threads, each computes 4 rows x 8 cols. LDS ~49KB -> 3 blocks/CU.
__global__ __launch_bounds__(256) void k_gemm128(const float* __restrict__ A,
                                                 const float* __restrict__ B,
                                                 const float* __restrict__ Cin,
                                                 const float* __restrict__ bias,
                                                 float* __restrict__ Cout, int M) {
    __shared__ float As[64 * 68];   // pad 64->68 to break bank conflicts
    __shared__ float Bs[64 * 128];
    int row0 = blockIdx.x * 64;
    int tx = threadIdx.x;
    int cg = tx & 15;   // col group: 8 cols
    int rg = tx >> 4;   // row group: 4 rows
    float acc[4][8];
    #pragma unroll
    for (int i = 0; i < 4; ++i)
        #pragma unroll
        for (int j = 0; j < 8; ++j) acc[i][j] = 0.0f;

    for (int k0 = 0; k0 < 128; k0 += 64) {
        // stage A slab: 64 rows x 64 k
        #pragma unroll
        for (int q = 0; q < 4; ++q) {
            int l = tx + q * 256;       // 0..1023 float4 slots
            int r = l >> 4;             // 16 float4 per row
            int c4 = l & 15;
            int grow = row0 + r;
            float4 v = make_float4(0.f, 0.f, 0.f, 0.f);
            if (grow < M) v = *(const float4*)(A + (size_t)grow * 128 + k0 + c4 * 4);
            *(float4*)(&As[r * 68 + c4 * 4]) = v;
        }
        // stage B slab: 64 k x 128 cols
        #pragma unroll
        for (int q = 0; q < 8; ++q) {
            int l = tx + q * 256;       // 0..2047 float4 slots
            int r = l >> 5;             // 32 float4 per row
            int c4 = l & 31;
            *(float4*)(&Bs[r * 128 + c4 * 4]) = *(const float4*)(B + (size_t)(k0 + r) * 128 + c4 * 4);
        }
        __syncthreads();
        #pragma unroll 8
        for (int k = 0; k < 64; ++k) {
            float a0 = As[(rg * 4 + 0) * 68 + k];
            float a1 = As[(rg * 4 + 1) * 68 + k];
            float a2 = As[(rg * 4 + 2) * 68 + k];
            float a3 = As[(rg * 4 + 3) * 68 + k];
            float4 b0 = *(const float4*)(&Bs[k * 128 + cg * 8]);
            float4 b1 = *(const float4*)(&Bs[k * 128 + cg * 8 + 4]);
            float bb[8] = {b0.x, b0.y, b0.z, b0.w, b1.x, b1.y, b1.z, b1.w};
            float aa[4] = {a0, a1, a2, a3};
            #pragma unroll
            for (int i = 0; i < 4; ++i)
                #pragma unroll
                for (int j = 0; j < 8; ++j) acc[i][j] = fmaf(aa[i], bb[j], acc[i][j]);
        }
        __syncthreads();
    }
    // epilogue
    #pragma unroll
    for (int i = 0; i < 4; ++i) {
        int grow = row0 + rg * 4 + i;
        if (grow >= M) continue;
        #pragma unroll
        for (int jq = 0; jq < 2; ++jq) {
            int c = cg * 8 + jq * 4;
            float4 v = make_float4(acc[i][jq * 4 + 0], acc[i][jq * 4 + 1],
                                   acc[i][jq * 4 + 2], acc[i][jq * 4 + 3]);
            if (bias) {
                float4 bv = *(const float4*)(bias + c);
                v.x += bv.x; v.y += bv.y; v.z += bv.z; v.w += bv.w;
            }
            if (Cin) {
                float4 cv = *(const float4*)(Cin + (size_t)grow * 128 + c);
                v.x += cv.x; v.y += cv.y; v.z += cv.z; v.w += cv.w;
            }
            *(float4*)(Cout + (size_t)grow * 128 + c) = v;
        }
    }
}

// One wave per node: agg[i,:] = sum_j t[col_j,:] * lerp(T, d_j)
__global__ __launch_bounds__(256) void k_agg(const float* __restrict__ t,
                                             const float* __restrict__ T,
                                             const int* __restrict__ deg,
                                             const int* __restrict__ ecol,
                                             const float* __restrict__ ed,
                                             float* __restrict__ agg) {
    int wave = (blockIdx.x * blockDim.x + threadIdx.x) >> 6;
    int lane = threadIdx.x & 63;
    if (wave >= NN) return;
    int i = wave;
    int dg = min(deg[i], ELLS);
    float ax = 0.f, ay = 0.f;
    const int base = i * ELLS;
    for (int j = 0; j < dg; ++j) {
        int c = ecol[base + j];
        float dv = ed[base + j];
        float u = dv * ((float)(NB - 1) / DMAXT);
        int b = (int)u;
        float fr = u - (float)b;
        if (b > NB - 2) { b = NB - 2; fr = 1.0f; }
        float2 tv = *(const float2*)(t + (size_t)c * HD + 2 * lane);
        float2 T0 = *(const float2*)(T + (size_t)b * FD + 2 * lane);
        float2 T1 = *(const float2*)(T + (size_t)(b + 1) * FD + 2 * lane);
        float wx = fmaf(fr, T1.x - T0.x, T0.x);
        float wy = fmaf(fr, T1.y - T0.y, T0.y);
        ax = fmaf(tv.x, wx, ax);
        ay = fmaf(tv.y, wy, ay);
    }
    float2 o; o.x = ax; o.y = ay;
    *(float2*)(agg + (size_t)i * FD + 2 * lane) = o;
}

// One wave per node: g = ssp(h_i@w_g1+b_g1)@w_g2 + b_g2; atomicAdd into out[batch[i]]
__global__ __launch_bounds__(256) void k_readout(const float* __restrict__ h,
                                                 const int* __restrict__ batch,
                                                 const float* __restrict__ w_g1,
                                                 const float* __restrict__ b_g1,
                                                 const float* __restrict__ w_g2,
                                                 const float* __restrict__ b_g2,
                                                 float* __restrict__ out) {
    __shared__ float hrow[4][HD];
    int lane = threadIdx.x & 63;
    int wi = threadIdx.x >> 6;
    int i = blockIdx.x * 4 + wi;     // NN % 4 == 0, always valid
    float2 hv = *(const float2*)(h + (size_t)i * HD + 2 * lane);
    hrow[wi][2 * lane] = hv.x;
    hrow[wi][2 * lane + 1] = hv.y;
    __syncthreads();
    float acc = b_g1[lane];
    #pragma unroll 8
    for (int k = 0; k < HD; ++k) acc = fmaf(hrow[wi][k], w_g1[k * 64 + lane], acc);
    float g = sspf(acc) * w_g2[lane];
    #pragma unroll
    for (int o = 32; o > 0; o >>= 1) g += __shfl_down(g, o, 64);
    if (lane == 0) atomicAdd(&out[batch[i]], g + b_g2[0]);
}

extern "C" void kernel_launch(void* const* d_in, const int* in_sizes, int n_in,
                              void* d_out, int out_size, void* d_ws, size_t ws_size,
                              hipStream_t stream) {
    const int*   charges = (const int*)d_in[0];
    const float* coords  = (const float*)d_in[1];
    const int*   eidx    = (const int*)d_in[2];
    const int*   batch   = (const int*)d_in[3];
    const float* emb     = (const float*)d_in[4];
    const float* w_e1    = (const float*)d_in[5];
    const float* b_e1    = (const float*)d_in[6];
    const float* w_e2    = (const float*)d_in[7];
    const float* b_e2    = (const float*)d_in[8];
    const float* w_el    = (const float*)d_in[9];
    const float* w_nm    = (const float*)d_in[10];
    const float* b_nm    = (const float*)d_in[11];
    const float* w_g1    = (const float*)d_in[12];
    const float* b_g1    = (const float*)d_in[13];
    const float* w_g2    = (const float*)d_in[14];
    const float* b_g2    = (const float*)d_in[15];
    float* out = (float*)d_out;

    char* ws = (char*)d_ws;
    size_t off = 0;
    auto alloc = [&](size_t bytes) -> char* {
        char* p = ws + off;
        off += (bytes + 255) & ~(size_t)255;
        return p;
    };
    float* h   = (float*)alloc((size_t)NN * HD * 4);        // 25.6 MB
    float* t   = (float*)alloc((size_t)NN * FD * 4);        // 25.6 MB
    float* agg = (float*)alloc((size_t)NN * FD * 4);        // 25.6 MB
    float* T   = (float*)alloc((size_t)NB * FD * 4);        // 2 MB
    int*   deg = (int*)alloc((size_t)NN * 4);               // 0.2 MB
    int*   ecol= (int*)alloc((size_t)NN * ELLS * 4);        // 16 MB
    float* ed  = (float*)alloc((size_t)NN * ELLS * 4);      // 16 MB
    if (off > ws_size) return;  // workspace too small -> fail visibly, no OOB

    hipMemsetAsync(deg, 0, (size_t)NN * 4, stream);
    hipMemsetAsync(out, 0, (size_t)NGR * 4, stream);

    k_embed<<<(NN * (HD / 4) + 255) / 256, 256, 0, stream>>>(charges, emb, h);
    k_table<<<NB, 128, 0, stream>>>(w_e1, b_e1, w_e2, b_e2, T);
    k_edgeprep<<<(NE + 255) / 256, 256, 0, stream>>>(eidx, coords, deg, ecol, ed);

    for (int it = 0; it < 2; ++it) {
        k_gemm128<<<(NN + 63) / 64, 256, 0, stream>>>(h, w_el, nullptr, nullptr, t, NN);
        k_agg<<<NN / 4, 256, 0, stream>>>(t, T, deg, ecol, ed, agg);
        k_gemm128<<<(NN + 63) / 64, 256, 0, stream>>>(agg, w_nm, h, b_nm, h, NN);
    }
    k_readout<<<NN / 4, 256, 0, stream>>>(h, batch, w_g1, b_g1, w_g2, b_g2, out);
}

// Round 2
// 579.157 us; speedup vs baseline: 1.1139x; 1.1139x over previous
//
#include <hip/hip_runtime.h>
#include <hip/hip_bf16.h>

// SchNet forward on MI355X.
// Strategy: W(d) depends only on scalar d -> precompute 4096x128 lookup table
// (linear interp, rel err ~3e-5), ELL bucketing by destination row to make
// segment_sum atomic-free, fp32 register-tiled GEMMs for the 128x128 mixes.
// R2: readout rewritten as LDS-tiled GEMM (was latency-bound at 134us:
//     per-wave re-stream of w_g1 from global, VALUBusy 20%).

#define NN 50000      // nodes
#define NE 800000     // edges
#define NGR 512       // graphs
#define HD 128        // hidden
#define FD 128        // filters
#define GG 50         // gaussians
#define NB 4096       // table bins
#define DMAXT 12.0f   // table covers [0,12]; beyond, W is constant (gauss < e^-48)
#define ELLS 80       // ELL stride; deg ~ Poisson(16), P(deg>80) ~ 0

#define DELTA (10.0f/49.0f)
#define COEFF (-0.5f/(DELTA*DELTA))

static __device__ __forceinline__ float sspf(float x) {
    // softplus(x) - log(2), numerically stable
    return fmaxf(x, 0.0f) + log1pf(expf(-fabsf(x))) - 0.69314718055994531f;
}

// h[i,:] = emb[charges[i],:]  (float4-vectorized)
__global__ __launch_bounds__(256) void k_embed(const int* __restrict__ charges,
                                               const float* __restrict__ emb,
                                               float* __restrict__ h) {
    int idx = blockIdx.x * blockDim.x + threadIdx.x;   // over NN*32 float4s
    if (idx >= NN * (HD / 4)) return;
    int i  = idx >> 5;          // node
    int f4 = idx & 31;          // float4 within row
    ((float4*)h)[idx] = ((const float4*)emb)[charges[i] * (HD / 4) + f4];
}

// Build table T[b,:] = ssp(gauss(d_b)@w_e1 + b_e1)@w_e2 + b_e2,  d_b = b*DMAXT/(NB-1)
__global__ __launch_bounds__(128) void k_table(const float* __restrict__ w_e1,
                                               const float* __restrict__ b_e1,
                                               const float* __restrict__ w_e2,
                                               const float* __restrict__ b_e2,
                                               float* __restrict__ T) {
    __shared__ float a[GG];
    __shared__ float y[FD];
    int b = blockIdx.x;
    int f = threadIdx.x;          // 0..127
    float d = (float)b * (DMAXT / (float)(NB - 1));
    if (f < GG) {
        float off = (float)f * DELTA;
        float t = d - off;
        a[f] = expf(COEFF * t * t);
    }
    __syncthreads();
    float acc = b_e1[f];
    #pragma unroll 10
    for (int g = 0; g < GG; ++g) acc = fmaf(a[g], w_e1[g * FD + f], acc);
    y[f] = sspf(acc);
    __syncthreads();
    float acc2 = b_e2[f];
    #pragma unroll 8
    for (int k = 0; k < FD; ++k) acc2 = fmaf(y[k], w_e2[k * FD + f], acc2);
    T[b * FD + f] = acc2;
}

// Per edge: d = |coords[row]-coords[col]|; bucket (col, d) into ELL slot of row.
__global__ __launch_bounds__(256) void k_edgeprep(const int* __restrict__ eidx,
                                                  const float* __restrict__ coords,
                                                  int* __restrict__ deg,
                                                  int* __restrict__ ecol,
                                                  float* __restrict__ ed) {
    int e = blockIdx.x * blockDim.x + threadIdx.x;
    if (e >= NE) return;
    int r = eidx[e];
    int c = eidx[NE + e];
    float dx = coords[r * 3 + 0] - coords[c * 3 + 0];
    float dy = coords[r * 3 + 1] - coords[c * 3 + 1];
    float dz = coords[r * 3 + 2] - coords[c * 3 + 2];
    float d = sqrtf(dx * dx + dy * dy + dz * dz);
    int pos = atomicAdd(&deg[r], 1);
    if (pos < ELLS) {
        ecol[r * ELLS + pos] = c;
        ed[r * ELLS + pos] = d;
    }
}

// Cout[M,128] = A[M,128] @ B[128,128] (+ Cin) (+ bias).  64-row tiles, kc=64 slabs.
// 256 threads, each computes 4 rows x 8 cols. LDS ~49KB -> 3 blocks/CU.
__global__ __launch_bounds__(256) void k_gemm128(const float* __restrict__ A,
                                                 const float* __restrict__ B,
                                                 const float* __restrict__ Cin,
                                                 const float* __restrict__ bias,
                                                 float* __restrict__ Cout, int M) {
    __shared__ float As[64 * 68];   // pad 64->68 to break bank conflicts
    __shared__ float Bs[64 * 128];
    int row0 = blockIdx.x * 64;
    int tx = threadIdx.x;
    int cg = tx & 15;   // col group: 8 cols
    int rg = tx >> 4;   // row group: 4 rows
    float acc[4][8];
    #pragma unroll
    for (int i = 0; i < 4; ++i)
        #pragma unroll
        for (int j = 0; j < 8; ++j) acc[i][j] = 0.0f;

    for (int k0 = 0; k0 < 128; k0 += 64) {
        // stage A slab: 64 rows x 64 k
        #pragma unroll
        for (int q = 0; q < 4; ++q) {
            int l = tx + q * 256;       // 0..1023 float4 slots
            int r = l >> 4;             // 16 float4 per row
            int c4 = l & 15;
            int grow = row0 + r;
            float4 v = make_float4(0.f, 0.f, 0.f, 0.f);
            if (grow < M) v = *(const float4*)(A + (size_t)grow * 128 + k0 + c4 * 4);
            *(float4*)(&As[r * 68 + c4 * 4]) = v;
        }
        // stage B slab: 64 k x 128 cols
        #pragma unroll
        for (int q = 0; q < 8; ++q) {
            int l = tx + q * 256;       // 0..2047 float4 slots
            int r = l >> 5;             // 32 float4 per row
            int c4 = l & 31;
            *(float4*)(&Bs[r * 128 + c4 * 4]) = *(const float4*)(B + (size_t)(k0 + r) * 128 + c4 * 4);
        }
        __syncthreads();
        #pragma unroll 8
        for (int k = 0; k < 64; ++k) {
            float a0 = As[(rg * 4 + 0) * 68 + k];
            float a1 = As[(rg * 4 + 1) * 68 + k];
            float a2 = As[(rg * 4 + 2) * 68 + k];
            float a3 = As[(rg * 4 + 3) * 68 + k];
            float4 b0 = *(const float4*)(&Bs[k * 128 + cg * 8]);
            float4 b1 = *(const float4*)(&Bs[k * 128 + cg * 8 + 4]);
            float bb[8] = {b0.x, b0.y, b0.z, b0.w, b1.x, b1.y, b1.z, b1.w};
            float aa[4] = {a0, a1, a2, a3};
            #pragma unroll
            for (int i = 0; i < 4; ++i)
                #pragma unroll
                for (int j = 0; j < 8; ++j) acc[i][j] = fmaf(aa[i], bb[j], acc[i][j]);
        }
        __syncthreads();
    }
    // epilogue
    #pragma unroll
    for (int i = 0; i < 4; ++i) {
        int grow = row0 + rg * 4 + i;
        if (grow >= M) continue;
        #pragma unroll
        for (int jq = 0; jq < 2; ++jq) {
            int c = cg * 8 + jq * 4;
            float4 v = make_float4(acc[i][jq * 4 + 0], acc[i][jq * 4 + 1],
                                   acc[i][jq * 4 + 2], acc[i][jq * 4 + 3]);
            if (bias) {
                float4 bv = *(const float4*)(bias + c);
                v.x += bv.x; v.y += bv.y; v.z += bv.z; v.w += bv.w;
            }
            if (Cin) {
                float4 cv = *(const float4*)(Cin + (size_t)grow * 128 + c);
                v.x += cv.x; v.y += cv.y; v.z += cv.z; v.w += cv.w;
            }
            *(float4*)(Cout + (size_t)grow * 128 + c) = v;
        }
    }
}

// One wave per node: agg[i,:] = sum_j t[col_j,:] * lerp(T, d_j)
__global__ __launch_bounds__(256) void k_agg(const float* __restrict__ t,
                                             const float* __restrict__ T,
                                             const int* __restrict__ deg,
                                             const int* __restrict__ ecol,
                                             const float* __restrict__ ed,
                                             float* __restrict__ agg) {
    int wave = (blockIdx.x * blockDim.x + threadIdx.x) >> 6;
    int lane = threadIdx.x & 63;
    if (wave >= NN) return;
    int i = wave;
    int dg = min(deg[i], ELLS);
    float ax = 0.f, ay = 0.f;
    const int base = i * ELLS;
    for (int j = 0; j < dg; ++j) {
        int c = ecol[base + j];
        float dv = ed[base + j];
        float u = dv * ((float)(NB - 1) / DMAXT);
        int b = (int)u;
        float fr = u - (float)b;
        if (b > NB - 2) { b = NB - 2; fr = 1.0f; }
        float2 tv = *(const float2*)(t + (size_t)c * HD + 2 * lane);
        float2 T0 = *(const float2*)(T + (size_t)b * FD + 2 * lane);
        float2 T1 = *(const float2*)(T + (size_t)(b + 1) * FD + 2 * lane);
        float wx = fmaf(fr, T1.x - T0.x, T0.x);
        float wy = fmaf(fr, T1.y - T0.y, T0.y);
        ax = fmaf(tv.x, wx, ax);
        ay = fmaf(tv.y, wy, ay);
    }
    float2 o; o.x = ax; o.y = ay;
    *(float2*)(agg + (size_t)i * FD + 2 * lane) = o;
}

// Readout as tiled GEMM: per 64-row tile, G1 = ssp(hTile@w_g1 + b_g1),
// g = G1@w_g2 + b_g2, atomicAdd per row into out[batch[row]].
// 256 threads: cg=tx&15 -> 4 cols, rg=tx>>4 -> 4 rows. w_g1 staged in LDS once.
__global__ __launch_bounds__(256) void k_readout(const float* __restrict__ h,
                                                 const int* __restrict__ batch,
                                                 const float* __restrict__ w_g1,
                                                 const float* __restrict__ b_g1,
                                                 const float* __restrict__ w_g2,
                                                 const float* __restrict__ b_g2,
                                                 float* __restrict__ out) {
    __shared__ float As[64 * 132];   // h tile: 64 rows x 128 k, pad -> 132
    __shared__ float Bs[128 * 64];   // w_g1 (row-major, k x col)
    int row0 = blockIdx.x * 64;
    int tx = threadIdx.x;
    int cg = tx & 15;    // 4 cols each: cols cg*4..cg*4+3
    int rg = tx >> 4;    // 4 rows each: rows rg*4..rg*4+3

    // stage A: 64 rows x 32 float4
    #pragma unroll
    for (int q = 0; q < 8; ++q) {
        int l = tx + q * 256;        // 0..2047
        int r = l >> 5;
        int c4 = l & 31;
        int grow = row0 + r;
        float4 v = make_float4(0.f, 0.f, 0.f, 0.f);
        if (grow < NN) v = *(const float4*)(h + (size_t)grow * 128 + c4 * 4);
        *(float4*)(&As[r * 132 + c4 * 4]) = v;
    }
    // stage B: 128 rows x 16 float4
    #pragma unroll
    for (int q = 0; q < 8; ++q) {
        int l = tx + q * 256;        // 0..2047
        int r = l >> 4;
        int c4 = l & 15;
        *(float4*)(&Bs[r * 64 + c4 * 4]) = *(const float4*)(w_g1 + (size_t)r * 64 + c4 * 4);
    }
    __syncthreads();

    float4 binit = *(const float4*)(b_g1 + cg * 4);
    float acc[4][4];
    #pragma unroll
    for (int i = 0; i < 4; ++i) {
        acc[i][0] = binit.x; acc[i][1] = binit.y;
        acc[i][2] = binit.z; acc[i][3] = binit.w;
    }
    #pragma unroll 8
    for (int k = 0; k < 128; ++k) {
        float a0 = As[(rg * 4 + 0) * 132 + k];
        float a1 = As[(rg * 4 + 1) * 132 + k];
        float a2 = As[(rg * 4 + 2) * 132 + k];
        float a3 = As[(rg * 4 + 3) * 132 + k];
        float4 b4 = *(const float4*)(&Bs[k * 64 + cg * 4]);
        float aa[4] = {a0, a1, a2, a3};
        float bb[4] = {b4.x, b4.y, b4.z, b4.w};
        #pragma unroll
        for (int i = 0; i < 4; ++i)
            #pragma unroll
            for (int j = 0; j < 4; ++j) acc[i][j] = fmaf(aa[i], bb[j], acc[i][j]);
    }

    // epilogue: p_i = sum_j ssp(acc[i][j]) * w_g2[cg*4+j]; reduce over 16-lane col groups
    float4 w2 = *(const float4*)(w_g2 + cg * 4);
    float bg2 = b_g2[0];
    #pragma unroll
    for (int i = 0; i < 4; ++i) {
        float p = sspf(acc[i][0]) * w2.x + sspf(acc[i][1]) * w2.y
                + sspf(acc[i][2]) * w2.z + sspf(acc[i][3]) * w2.w;
        p += __shfl_down(p, 8, 64);
        p += __shfl_down(p, 4, 64);
        p += __shfl_down(p, 2, 64);
        p += __shfl_down(p, 1, 64);
        if (cg == 0) {
            int row = row0 + rg * 4 + i;
            if (row < NN) atomicAdd(&out[batch[row]], p + bg2);
        }
    }
}

extern "C" void kernel_launch(void* const* d_in, const int* in_sizes, int n_in,
                              void* d_out, int out_size, void* d_ws, size_t ws_size,
                              hipStream_t stream) {
    const int*   charges = (const int*)d_in[0];
    const float* coords  = (const float*)d_in[1];
    const int*   eidx    = (const int*)d_in[2];
    const int*   batch   = (const int*)d_in[3];
    const float* emb     = (const float*)d_in[4];
    const float* w_e1    = (const float*)d_in[5];
    const float* b_e1    = (const float*)d_in[6];
    const float* w_e2    = (const float*)d_in[7];
    const float* b_e2    = (const float*)d_in[8];
    const float* w_el    = (const float*)d_in[9];
    const float* w_nm    = (const float*)d_in[10];
    const float* b_nm    = (const float*)d_in[11];
    const float* w_g1    = (const float*)d_in[12];
    const float* b_g1    = (const float*)d_in[13];
    const float* w_g2    = (const float*)d_in[14];
    const float* b_g2    = (const float*)d_in[15];
    float* out = (float*)d_out;

    char* ws = (char*)d_ws;
    size_t off = 0;
    auto alloc = [&](size_t bytes) -> char* {
        char* p = ws + off;
        off += (bytes + 255) & ~(size_t)255;
        return p;
    };
    float* h   = (float*)alloc((size_t)NN * HD * 4);        // 25.6 MB
    float* t   = (float*)alloc((size_t)NN * FD * 4);        // 25.6 MB
    float* agg = (float*)alloc((size_t)NN * FD * 4);        // 25.6 MB
    float* T   = (float*)alloc((size_t)NB * FD * 4);        // 2 MB
    int*   deg = (int*)alloc((size_t)NN * 4);               // 0.2 MB
    int*   ecol= (int*)alloc((size_t)NN * ELLS * 4);        // 16 MB
    float* ed  = (float*)alloc((size_t)NN * ELLS * 4);      // 16 MB
    if (off > ws_size) return;  // workspace too small -> fail visibly, no OOB

    hipMemsetAsync(deg, 0, (size_t)NN * 4, stream);
    hipMemsetAsync(out, 0, (size_t)NGR * 4, stream);

    k_embed<<<(NN * (HD / 4) + 255) / 256, 256, 0, stream>>>(charges, emb, h);
    k_table<<<NB, 128, 0, stream>>>(w_e1, b_e1, w_e2, b_e2, T);
    k_edgeprep<<<(NE + 255) / 256, 256, 0, stream>>>(eidx, coords, deg, ecol, ed);

    for (int it = 0; it < 2; ++it) {
        k_gemm128<<<(NN + 63) / 64, 256, 0, stream>>>(h, w_el, nullptr, nullptr, t, NN);
        k_agg<<<NN / 4, 256, 0, stream>>>(t, T, deg, ecol, ed, agg);
        k_gemm128<<<(NN + 63) / 64, 256, 0, stream>>>(agg, w_nm, h, b_nm, h, NN);
    }
    k_readout<<<(NN + 63) / 64, 256, 0, stream>>>(h, batch, w_g1, b_g1, w_g2, b_g2, out);
}

// Round 3
// 515.233 us; speedup vs baseline: 1.2520x; 1.1241x over previous
//
#include <hip/hip_runtime.h>
#include <hip/hip_bf16.h>

// SchNet forward on MI355X.
// Strategy: W(d) depends only on scalar d -> precompute 4096x128 lookup table
// (linear interp, rel err ~3e-5), ELL bucketing by destination row to make
// segment_sum atomic-free, fp32 register-tiled GEMMs for the 128x128 mixes.
// R2: readout rewritten as LDS-tiled GEMM (was 134us latency-bound).
// R3: k_agg was latency-bound (VALUBusy 26%, 2.45TB/s L2-miss traffic,
//     serial ecol->t dependent chain). Now: batch index loads + 8x-unrolled
//     broadcast inner loop (8 concurrent gathers/wave) + t stored bf16
//     (halves gather bytes). ELL rows padded to x8 with d=-1 sentinels.

#define NN 50000      // nodes
#define NE 800000     // edges
#define NGR 512       // graphs
#define HD 128        // hidden
#define FD 128        // filters
#define GG 50         // gaussians
#define NB 4096       // table bins
#define DMAXT 12.0f   // table covers [0,12]; beyond, W is constant (gauss < e^-48)
#define ELLS 80       // ELL stride (multiple of 8); deg ~ Poisson(16)

#define DELTA (10.0f/49.0f)
#define COEFF (-0.5f/(DELTA*DELTA))

static __device__ __forceinline__ float sspf(float x) {
    // softplus(x) - log(2), numerically stable
    return fmaxf(x, 0.0f) + log1pf(expf(-fabsf(x))) - 0.69314718055994531f;
}

static __device__ __forceinline__ float bf2f(unsigned short b) {
    union { unsigned int u; float f; } v; v.u = ((unsigned int)b) << 16; return v.f;
}

// h[i,:] = emb[charges[i],:]  (float4-vectorized)
__global__ __launch_bounds__(256) void k_embed(const int* __restrict__ charges,
                                               const float* __restrict__ emb,
                                               float* __restrict__ h) {
    int idx = blockIdx.x * blockDim.x + threadIdx.x;   // over NN*32 float4s
    if (idx >= NN * (HD / 4)) return;
    int i  = idx >> 5;          // node
    int f4 = idx & 31;          // float4 within row
    ((float4*)h)[idx] = ((const float4*)emb)[charges[i] * (HD / 4) + f4];
}

// Build table T[b,:] = ssp(gauss(d_b)@w_e1 + b_e1)@w_e2 + b_e2,  d_b = b*DMAXT/(NB-1)
__global__ __launch_bounds__(128) void k_table(const float* __restrict__ w_e1,
                                               const float* __restrict__ b_e1,
                                               const float* __restrict__ w_e2,
                                               const float* __restrict__ b_e2,
                                               float* __restrict__ T) {
    __shared__ float a[GG];
    __shared__ float y[FD];
    int b = blockIdx.x;
    int f = threadIdx.x;          // 0..127
    float d = (float)b * (DMAXT / (float)(NB - 1));
    if (f < GG) {
        float off = (float)f * DELTA;
        float t = d - off;
        a[f] = expf(COEFF * t * t);
    }
    __syncthreads();
    float acc = b_e1[f];
    #pragma unroll 10
    for (int g = 0; g < GG; ++g) acc = fmaf(a[g], w_e1[g * FD + f], acc);
    y[f] = sspf(acc);
    __syncthreads();
    float acc2 = b_e2[f];
    #pragma unroll 8
    for (int k = 0; k < FD; ++k) acc2 = fmaf(y[k], w_e2[k * FD + f], acc2);
    T[b * FD + f] = acc2;
}

// Per edge: d = |coords[row]-coords[col]|; bucket (col, d) into ELL slot of row.
__global__ __launch_bounds__(256) void k_edgeprep(const int* __restrict__ eidx,
                                                  const float* __restrict__ coords,
                                                  int* __restrict__ deg,
                                                  int* __restrict__ ecol,
                                                  float* __restrict__ ed) {
    int e = blockIdx.x * blockDim.x + threadIdx.x;
    if (e >= NE) return;
    int r = eidx[e];
    int c = eidx[NE + e];
    float dx = coords[r * 3 + 0] - coords[c * 3 + 0];
    float dy = coords[r * 3 + 1] - coords[c * 3 + 1];
    float dz = coords[r * 3 + 2] - coords[c * 3 + 2];
    float d = sqrtf(dx * dx + dy * dy + dz * dz);
    int pos = atomicAdd(&deg[r], 1);
    if (pos < ELLS) {
        ecol[r * ELLS + pos] = c;
        ed[r * ELLS + pos] = d;
    }
}

// Pad each ELL row up to a multiple of 8 with sentinel (c=0, d=-1).
__global__ __launch_bounds__(256) void k_ellpad(const int* __restrict__ deg,
                                                int* __restrict__ ecol,
                                                float* __restrict__ ed) {
    int i = blockIdx.x * blockDim.x + threadIdx.x;
    if (i >= NN) return;
    int dg = min(deg[i], ELLS);
    int dgp = (dg + 7) & ~7;           // <= ELLS since ELLS % 8 == 0
    for (int j = dg; j < dgp; ++j) {
        ecol[i * ELLS + j] = 0;
        ed[i * ELLS + j] = -1.0f;
    }
}

// Cout[M,128] = A[M,128] @ B[128,128] (+ Cin) (+ bias).  64-row tiles, kc=64 slabs.
// 256 threads, each computes 4 rows x 8 cols. If Cout16 != null, store bf16 there
// instead of fp32 to Cout.
__global__ __launch_bounds__(256) void k_gemm128(const float* __restrict__ A,
                                                 const float* __restrict__ B,
                                                 const float* __restrict__ Cin,
                                                 const float* __restrict__ bias,
                                                 float* __restrict__ Cout,
                                                 __hip_bfloat16* __restrict__ Cout16,
                                                 int M) {
    __shared__ float As[64 * 68];   // pad 64->68 to break bank conflicts
    __shared__ float Bs[64 * 128];
    int row0 = blockIdx.x * 64;
    int tx = threadIdx.x;
    int cg = tx & 15;   // col group: 8 cols
    int rg = tx >> 4;   // row group: 4 rows
    float acc[4][8];
    #pragma unroll
    for (int i = 0; i < 4; ++i)
        #pragma unroll
        for (int j = 0; j < 8; ++j) acc[i][j] = 0.0f;

    for (int k0 = 0; k0 < 128; k0 += 64) {
        #pragma unroll
        for (int q = 0; q < 4; ++q) {
            int l = tx + q * 256;       // 0..1023 float4 slots
            int r = l >> 4;             // 16 float4 per row
            int c4 = l & 15;
            int grow = row0 + r;
            float4 v = make_float4(0.f, 0.f, 0.f, 0.f);
            if (grow < M) v = *(const float4*)(A + (size_t)grow * 128 + k0 + c4 * 4);
            *(float4*)(&As[r * 68 + c4 * 4]) = v;
        }
        #pragma unroll
        for (int q = 0; q < 8; ++q) {
            int l = tx + q * 256;       // 0..2047 float4 slots
            int r = l >> 5;             // 32 float4 per row
            int c4 = l & 31;
            *(float4*)(&Bs[r * 128 + c4 * 4]) = *(const float4*)(B + (size_t)(k0 + r) * 128 + c4 * 4);
        }
        __syncthreads();
        #pragma unroll 8
        for (int k = 0; k < 64; ++k) {
            float a0 = As[(rg * 4 + 0) * 68 + k];
            float a1 = As[(rg * 4 + 1) * 68 + k];
            float a2 = As[(rg * 4 + 2) * 68 + k];
            float a3 = As[(rg * 4 + 3) * 68 + k];
            float4 b0 = *(const float4*)(&Bs[k * 128 + cg * 8]);
            float4 b1 = *(const float4*)(&Bs[k * 128 + cg * 8 + 4]);
            float bb[8] = {b0.x, b0.y, b0.z, b0.w, b1.x, b1.y, b1.z, b1.w};
            float aa[4] = {a0, a1, a2, a3};
            #pragma unroll
            for (int i = 0; i < 4; ++i)
                #pragma unroll
                for (int j = 0; j < 8; ++j) acc[i][j] = fmaf(aa[i], bb[j], acc[i][j]);
        }
        __syncthreads();
    }
    // epilogue
    #pragma unroll
    for (int i = 0; i < 4; ++i) {
        int grow = row0 + rg * 4 + i;
        if (grow >= M) continue;
        #pragma unroll
        for (int jq = 0; jq < 2; ++jq) {
            int c = cg * 8 + jq * 4;
            float4 v = make_float4(acc[i][jq * 4 + 0], acc[i][jq * 4 + 1],
                                   acc[i][jq * 4 + 2], acc[i][jq * 4 + 3]);
            if (bias) {
                float4 bv = *(const float4*)(bias + c);
                v.x += bv.x; v.y += bv.y; v.z += bv.z; v.w += bv.w;
            }
            if (Cin) {
                float4 cv = *(const float4*)(Cin + (size_t)grow * 128 + c);
                v.x += cv.x; v.y += cv.y; v.z += cv.z; v.w += cv.w;
            }
            if (Cout16) {
                __hip_bfloat16 o4[4];
                o4[0] = __float2bfloat16(v.x); o4[1] = __float2bfloat16(v.y);
                o4[2] = __float2bfloat16(v.z); o4[3] = __float2bfloat16(v.w);
                *(ushort4*)(Cout16 + (size_t)grow * 128 + c) = *(ushort4*)o4;
            } else {
                *(float4*)(Cout + (size_t)grow * 128 + c) = v;
            }
        }
    }
}

// One wave per node: agg[i,:] = sum_j t[col_j,:] * lerp(T, d_j)
// t is bf16. Indices/distances batch-loaded lane-parallel, then broadcast via
// shfl in an 8x-unrolled loop -> ~8 concurrent t-gathers per wave.
__global__ __launch_bounds__(256) void k_agg(const __hip_bfloat16* __restrict__ t,
                                             const float* __restrict__ T,
                                             const int* __restrict__ deg,
                                             const int* __restrict__ ecol,
                                             const float* __restrict__ ed,
                                             float* __restrict__ agg) {
    int wave = (blockIdx.x * blockDim.x + threadIdx.x) >> 6;
    int lane = threadIdx.x & 63;
    if (wave >= NN) return;
    int i = wave;
    int dg = min(deg[i], ELLS);
    int dgp = (dg + 7) & ~7;         // padded region has d = -1 sentinels
    const int base = i * ELLS;
    float ax = 0.f, ay = 0.f;
    for (int j0 = 0; j0 < dgp; j0 += 64) {
        int n = min(64, dgp - j0);   // multiple of 8
        int myc = 0, myb = 0;
        float myfr = 0.f, mym = 0.f;
        if (lane < n) {
            myc = ecol[base + j0 + lane];
            float dv = ed[base + j0 + lane];
            mym = (dv >= 0.f) ? 1.f : 0.f;
            float u = fmaxf(dv, 0.f) * ((float)(NB - 1) / DMAXT);
            int b = (int)u;
            float fr = u - (float)b;
            if (b > NB - 2) { b = NB - 2; fr = 1.0f; }
            myb = b; myfr = fr;
        }
        for (int j = 0; j < n; j += 8) {
            #pragma unroll
            for (int u = 0; u < 8; ++u) {
                int c    = __shfl(myc, j + u, 64);
                int b    = __shfl(myb, j + u, 64);
                float fr = __shfl(myfr, j + u, 64);
                float m  = __shfl(mym, j + u, 64);
                unsigned int tv = *(const unsigned int*)((const unsigned short*)t + (size_t)c * HD + 2 * lane);
                float tx = bf2f((unsigned short)(tv & 0xFFFFu));
                float ty = bf2f((unsigned short)(tv >> 16));
                float2 T0 = *(const float2*)(T + (size_t)b * FD + 2 * lane);
                float2 T1 = *(const float2*)(T + (size_t)(b + 1) * FD + 2 * lane);
                float wx = fmaf(fr, T1.x - T0.x, T0.x) * m;
                float wy = fmaf(fr, T1.y - T0.y, T0.y) * m;
                ax = fmaf(tx, wx, ax);
                ay = fmaf(ty, wy, ay);
            }
        }
    }
    float2 o; o.x = ax; o.y = ay;
    *(float2*)(agg + (size_t)i * FD + 2 * lane) = o;
}

// Readout as tiled GEMM: per 64-row tile, G1 = ssp(hTile@w_g1 + b_g1),
// g = G1@w_g2 + b_g2, atomicAdd per row into out[batch[row]].
__global__ __launch_bounds__(256) void k_readout(const float* __restrict__ h,
                                                 const int* __restrict__ batch,
                                                 const float* __restrict__ w_g1,
                                                 const float* __restrict__ b_g1,
                                                 const float* __restrict__ w_g2,
                                                 const float* __restrict__ b_g2,
                                                 float* __restrict__ out) {
    __shared__ float As[64 * 132];   // h tile: 64 rows x 128 k, pad -> 132
    __shared__ float Bs[128 * 64];   // w_g1 (row-major, k x col)
    int row0 = blockIdx.x * 64;
    int tx = threadIdx.x;
    int cg = tx & 15;    // 4 cols each
    int rg = tx >> 4;    // 4 rows each

    #pragma unroll
    for (int q = 0; q < 8; ++q) {
        int l = tx + q * 256;        // 0..2047
        int r = l >> 5;
        int c4 = l & 31;
        int grow = row0 + r;
        float4 v = make_float4(0.f, 0.f, 0.f, 0.f);
        if (grow < NN) v = *(const float4*)(h + (size_t)grow * 128 + c4 * 4);
        *(float4*)(&As[r * 132 + c4 * 4]) = v;
    }
    #pragma unroll
    for (int q = 0; q < 8; ++q) {
        int l = tx + q * 256;        // 0..2047
        int r = l >> 4;
        int c4 = l & 15;
        *(float4*)(&Bs[r * 64 + c4 * 4]) = *(const float4*)(w_g1 + (size_t)r * 64 + c4 * 4);
    }
    __syncthreads();

    float4 binit = *(const float4*)(b_g1 + cg * 4);
    float acc[4][4];
    #pragma unroll
    for (int i = 0; i < 4; ++i) {
        acc[i][0] = binit.x; acc[i][1] = binit.y;
        acc[i][2] = binit.z; acc[i][3] = binit.w;
    }
    #pragma unroll 8
    for (int k = 0; k < 128; ++k) {
        float a0 = As[(rg * 4 + 0) * 132 + k];
        float a1 = As[(rg * 4 + 1) * 132 + k];
        float a2 = As[(rg * 4 + 2) * 132 + k];
        float a3 = As[(rg * 4 + 3) * 132 + k];
        float4 b4 = *(const float4*)(&Bs[k * 64 + cg * 4]);
        float aa[4] = {a0, a1, a2, a3};
        float bb[4] = {b4.x, b4.y, b4.z, b4.w};
        #pragma unroll
        for (int i = 0; i < 4; ++i)
            #pragma unroll
            for (int j = 0; j < 4; ++j) acc[i][j] = fmaf(aa[i], bb[j], acc[i][j]);
    }

    float4 w2 = *(const float4*)(w_g2 + cg * 4);
    float bg2 = b_g2[0];
    #pragma unroll
    for (int i = 0; i < 4; ++i) {
        float p = sspf(acc[i][0]) * w2.x + sspf(acc[i][1]) * w2.y
                + sspf(acc[i][2]) * w2.z + sspf(acc[i][3]) * w2.w;
        p += __shfl_down(p, 8, 64);
        p += __shfl_down(p, 4, 64);
        p += __shfl_down(p, 2, 64);
        p += __shfl_down(p, 1, 64);
        if (cg == 0) {
            int row = row0 + rg * 4 + i;
            if (row < NN) atomicAdd(&out[batch[row]], p + bg2);
        }
    }
}

extern "C" void kernel_launch(void* const* d_in, const int* in_sizes, int n_in,
                              void* d_out, int out_size, void* d_ws, size_t ws_size,
                              hipStream_t stream) {
    const int*   charges = (const int*)d_in[0];
    const float* coords  = (const float*)d_in[1];
    const int*   eidx    = (const int*)d_in[2];
    const int*   batch   = (const int*)d_in[3];
    const float* emb     = (const float*)d_in[4];
    const float* w_e1    = (const float*)d_in[5];
    const float* b_e1    = (const float*)d_in[6];
    const float* w_e2    = (const float*)d_in[7];
    const float* b_e2    = (const float*)d_in[8];
    const float* w_el    = (const float*)d_in[9];
    const float* w_nm    = (const float*)d_in[10];
    const float* b_nm    = (const float*)d_in[11];
    const float* w_g1    = (const float*)d_in[12];
    const float* b_g1    = (const float*)d_in[13];
    const float* w_g2    = (const float*)d_in[14];
    const float* b_g2    = (const float*)d_in[15];
    float* out = (float*)d_out;

    char* ws = (char*)d_ws;
    size_t off = 0;
    auto alloc = [&](size_t bytes) -> char* {
        char* p = ws + off;
        off += (bytes + 255) & ~(size_t)255;
        return p;
    };
    float* h   = (float*)alloc((size_t)NN * HD * 4);          // 25.6 MB
    __hip_bfloat16* t = (__hip_bfloat16*)alloc((size_t)NN * FD * 2);  // 12.8 MB
    float* agg = (float*)alloc((size_t)NN * FD * 4);          // 25.6 MB
    float* T   = (float*)alloc((size_t)NB * FD * 4);          // 2 MB
    int*   deg = (int*)alloc((size_t)NN * 4);                 // 0.2 MB
    int*   ecol= (int*)alloc((size_t)NN * ELLS * 4);          // 16 MB
    float* ed  = (float*)alloc((size_t)NN * ELLS * 4);        // 16 MB
    if (off > ws_size) return;  // workspace too small -> fail visibly, no OOB

    hipMemsetAsync(deg, 0, (size_t)NN * 4, stream);
    hipMemsetAsync(out, 0, (size_t)NGR * 4, stream);

    k_embed<<<(NN * (HD / 4) + 255) / 256, 256, 0, stream>>>(charges, emb, h);
    k_table<<<NB, 128, 0, stream>>>(w_e1, b_e1, w_e2, b_e2, T);
    k_edgeprep<<<(NE + 255) / 256, 256, 0, stream>>>(eidx, coords, deg, ecol, ed);
    k_ellpad<<<(NN + 255) / 256, 256, 0, stream>>>(deg, ecol, ed);

    for (int it = 0; it < 2; ++it) {
        k_gemm128<<<(NN + 63) / 64, 256, 0, stream>>>(h, w_el, nullptr, nullptr, nullptr, t, NN);
        k_agg<<<NN / 4, 256, 0, stream>>>(t, T, deg, ecol, ed, agg);
        k_gemm128<<<(NN + 63) / 64, 256, 0, stream>>>(agg, w_nm, h, b_nm, h, nullptr, NN);
    }
    k_readout<<<(NN + 63) / 64, 256, 0, stream>>>(h, batch, w_g1, b_g1, w_g2, b_g2, out);
}

// Round 4
// 461.493 us; speedup vs baseline: 1.3978x; 1.1164x over previous
//
#include <hip/hip_runtime.h>
#include <hip/hip_bf16.h>

// SchNet forward on MI355X.
// Strategy: W(d) depends only on scalar d -> precompute 4096x128 lookup table
// (linear interp), ELL bucketing by destination row for atomic-free segment
// sum. R3: k_agg batched-broadcast gathers + bf16 t. R4: all GEMMs moved to
// bf16 MFMA (fp32 vector GEMMs were ~65us each, ~half of runtime); readout
// fused into its GEMM epilogue (was 80us, occupancy-starved at 2 blocks/CU).
// Residual stream h stays fp32; bf16 shadow copies feed MFMA A-operands.

#define NN 50000      // nodes
#define NE 800000     // edges
#define NGR 512       // graphs
#define HD 128        // hidden
#define FD 128        // filters
#define GG 50         // gaussians
#define NB 4096       // table bins
#define DMAXT 12.0f   // table covers [0,12]; beyond, W const (gauss < e^-48)
#define ELLS 80       // ELL stride (multiple of 8); deg ~ Poisson(16)
#define ASTR 136      // LDS row stride in bf16 elems (128+8: 16B-aligned, spreads banks)

#define DELTA (10.0f/49.0f)
#define COEFF (-0.5f/(DELTA*DELTA))

typedef __attribute__((ext_vector_type(8))) short bf16x8;
typedef __attribute__((ext_vector_type(4))) float f32x4;

static __device__ __forceinline__ float sspf(float x) {
    return fmaxf(x, 0.0f) + log1pf(expf(-fabsf(x))) - 0.69314718055994531f;
}
static __device__ __forceinline__ float bf2f(unsigned short b) {
    union { unsigned int u; float f; } v; v.u = ((unsigned int)b) << 16; return v.f;
}
static __device__ __forceinline__ unsigned short f2bf(float f) {
    union { float f; unsigned int u; } v; v.f = f;
    unsigned int r = v.u + 0x7FFF + ((v.u >> 16) & 1);   // round-nearest-even
    return (unsigned short)(r >> 16);
}

// h[i,:] = emb[charges[i],:]  fp32 + bf16 shadow
__global__ __launch_bounds__(256) void k_embed(const int* __restrict__ charges,
                                               const float* __restrict__ emb,
                                               float* __restrict__ h,
                                               unsigned short* __restrict__ hb) {
    int idx = blockIdx.x * blockDim.x + threadIdx.x;   // over NN*32 float4s
    if (idx >= NN * (HD / 4)) return;
    int i  = idx >> 5;
    int f4 = idx & 31;
    float4 v = ((const float4*)emb)[charges[i] * (HD / 4) + f4];
    ((float4*)h)[idx] = v;
    ushort4 o;
    o.x = f2bf(v.x); o.y = f2bf(v.y); o.z = f2bf(v.z); o.w = f2bf(v.w);
    *(ushort4*)(hb + (size_t)idx * 4) = o;
}

// Build table T[b,:] = ssp(gauss(d_b)@w_e1 + b_e1)@w_e2 + b_e2
__global__ __launch_bounds__(128) void k_table(const float* __restrict__ w_e1,
                                               const float* __restrict__ b_e1,
                                               const float* __restrict__ w_e2,
                                               const float* __restrict__ b_e2,
                                               float* __restrict__ T) {
    __shared__ float a[GG];
    __shared__ float y[FD];
    int b = blockIdx.x;
    int f = threadIdx.x;
    float d = (float)b * (DMAXT / (float)(NB - 1));
    if (f < GG) {
        float off = (float)f * DELTA;
        float t = d - off;
        a[f] = expf(COEFF * t * t);
    }
    __syncthreads();
    float acc = b_e1[f];
    #pragma unroll 10
    for (int g = 0; g < GG; ++g) acc = fmaf(a[g], w_e1[g * FD + f], acc);
    y[f] = sspf(acc);
    __syncthreads();
    float acc2 = b_e2[f];
    #pragma unroll 8
    for (int k = 0; k < FD; ++k) acc2 = fmaf(y[k], w_e2[k * FD + f], acc2);
    T[b * FD + f] = acc2;
}

// wT[n*K+k] = bf16(w[k*N+n])  (weight transpose + bf16 convert, tiny)
__global__ __launch_bounds__(256) void k_prepw(const float* __restrict__ w,
                                               unsigned short* __restrict__ wT,
                                               int K, int N) {
    int idx = blockIdx.x * blockDim.x + threadIdx.x;
    if (idx >= K * N) return;
    int n = idx / K, k = idx - n * K;
    wT[idx] = f2bf(w[k * N + n]);
}

// Per edge: bucket (col, d) into ELL slot of row.
__global__ __launch_bounds__(256) void k_edgeprep(const int* __restrict__ eidx,
                                                  const float* __restrict__ coords,
                                                  int* __restrict__ deg,
                                                  int* __restrict__ ecol,
                                                  float* __restrict__ ed) {
    int e = blockIdx.x * blockDim.x + threadIdx.x;
    if (e >= NE) return;
    int r = eidx[e];
    int c = eidx[NE + e];
    float dx = coords[r * 3 + 0] - coords[c * 3 + 0];
    float dy = coords[r * 3 + 1] - coords[c * 3 + 1];
    float dz = coords[r * 3 + 2] - coords[c * 3 + 2];
    float d = sqrtf(dx * dx + dy * dy + dz * dz);
    int pos = atomicAdd(&deg[r], 1);
    if (pos < ELLS) {
        ecol[r * ELLS + pos] = c;
        ed[r * ELLS + pos] = d;
    }
}

// Pad each ELL row up to a multiple of 8 with sentinel (c=0, d=-1).
__global__ __launch_bounds__(256) void k_ellpad(const int* __restrict__ deg,
                                                int* __restrict__ ecol,
                                                float* __restrict__ ed) {
    int i = blockIdx.x * blockDim.x + threadIdx.x;
    if (i >= NN) return;
    int dg = min(deg[i], ELLS);
    int dgp = (dg + 7) & ~7;
    for (int j = dg; j < dgp; ++j) {
        ecol[i * ELLS + j] = 0;
        ed[i * ELLS + j] = -1.0f;
    }
}

// MFMA GEMM: C[M,128] = A[M,128](bf16) @ BT[128,128]^T(bf16) (+Cin)(+bias).
// 64-row tiles, 4 waves; wave w computes rows 16w..16w+15 x all 128 cols via
// 16x16x32 bf16 MFMA. Fragment maps (verified layouts): A[m=lane&15][k=quad*8+j],
// B[k=quad*8+j][n=lane&15] (from BT), C/D row=quad*4+reg, col=lane&15.
__global__ __launch_bounds__(256) void k_gemm_mfma(const unsigned short* __restrict__ A,
                                                   const unsigned short* __restrict__ BT,
                                                   const float* __restrict__ Cin,
                                                   const float* __restrict__ bias,
                                                   float* __restrict__ Cout,
                                                   unsigned short* __restrict__ Cout16,
                                                   int M) {
    __shared__ unsigned short Als[64 * ASTR];    // 17.4 KB
    __shared__ unsigned short Bls[128 * ASTR];   // 34.8 KB
    int tx = threadIdx.x;
    int row0 = blockIdx.x * 64;
    #pragma unroll
    for (int q = 0; q < 4; ++q) {            // A: 64 rows x 16 chunks of 16B
        int l = tx + q * 256;
        int r = l >> 4, c = l & 15;
        int grow = row0 + r;
        uint4 v = make_uint4(0u, 0u, 0u, 0u);
        if (grow < M) v = *(const uint4*)(A + (size_t)grow * 128 + c * 8);
        *(uint4*)(&Als[r * ASTR + c * 8]) = v;
    }
    #pragma unroll
    for (int q = 0; q < 8; ++q) {            // BT: 128 rows x 16 chunks
        int l = tx + q * 256;
        int r = l >> 4, c = l & 15;
        *(uint4*)(&Bls[r * ASTR + c * 8]) = *(const uint4*)(BT + (size_t)r * 128 + c * 8);
    }
    __syncthreads();

    int w = tx >> 6, lane = tx & 63;
    int m = lane & 15, quad = lane >> 4;
    f32x4 acc[8];
    #pragma unroll
    for (int ct = 0; ct < 8; ++ct) acc[ct] = (f32x4){0.f, 0.f, 0.f, 0.f};
    #pragma unroll
    for (int s = 0; s < 4; ++s) {
        bf16x8 a = *(const bf16x8*)(&Als[(w * 16 + m) * ASTR + s * 32 + quad * 8]);
        #pragma unroll
        for (int ct = 0; ct < 8; ++ct) {
            bf16x8 b = *(const bf16x8*)(&Bls[(ct * 16 + m) * ASTR + s * 32 + quad * 8]);
            acc[ct] = __builtin_amdgcn_mfma_f32_16x16x32_bf16(a, b, acc[ct], 0, 0, 0);
        }
    }
    #pragma unroll
    for (int r = 0; r < 4; ++r) {
        int grow = row0 + w * 16 + quad * 4 + r;
        if (grow >= M) continue;
        #pragma unroll
        for (int ct = 0; ct < 8; ++ct) {
            int col = ct * 16 + m;
            float v = acc[ct][r];
            if (bias) v += bias[col];
            if (Cin)  v += Cin[(size_t)grow * 128 + col];
            if (Cout)   Cout[(size_t)grow * 128 + col] = v;
            if (Cout16) Cout16[(size_t)grow * 128 + col] = f2bf(v);
        }
    }
}

// One wave per node: agg[i,:] = sum_j t[col_j,:] * lerp(T, d_j).  t bf16 in,
// agg bf16 out. Batched index loads + 8x broadcast unroll for gather MLP.
__global__ __launch_bounds__(256) void k_agg(const unsigned short* __restrict__ t,
                                             const float* __restrict__ T,
                                             const int* __restrict__ deg,
                                             const int* __restrict__ ecol,
                                             const float* __restrict__ ed,
                                             unsigned short* __restrict__ agg) {
    int wave = (blockIdx.x * blockDim.x + threadIdx.x) >> 6;
    int lane = threadIdx.x & 63;
    if (wave >= NN) return;
    int i = wave;
    int dg = min(deg[i], ELLS);
    int dgp = (dg + 7) & ~7;
    const int base = i * ELLS;
    float ax = 0.f, ay = 0.f;
    for (int j0 = 0; j0 < dgp; j0 += 64) {
        int n = min(64, dgp - j0);
        int myc = 0, myb = 0;
        float myfr = 0.f, mym = 0.f;
        if (lane < n) {
            myc = ecol[base + j0 + lane];
            float dv = ed[base + j0 + lane];
            mym = (dv >= 0.f) ? 1.f : 0.f;
            float u = fmaxf(dv, 0.f) * ((float)(NB - 1) / DMAXT);
            int b = (int)u;
            float fr = u - (float)b;
            if (b > NB - 2) { b = NB - 2; fr = 1.0f; }
            myb = b; myfr = fr;
        }
        for (int j = 0; j < n; j += 8) {
            #pragma unroll
            for (int u = 0; u < 8; ++u) {
                int c    = __shfl(myc, j + u, 64);
                int b    = __shfl(myb, j + u, 64);
                float fr = __shfl(myfr, j + u, 64);
                float msk = __shfl(mym, j + u, 64);
                unsigned int tv = *(const unsigned int*)(t + (size_t)c * HD + 2 * lane);
                float tx = bf2f((unsigned short)(tv & 0xFFFFu));
                float ty = bf2f((unsigned short)(tv >> 16));
                float2 T0 = *(const float2*)(T + (size_t)b * FD + 2 * lane);
                float2 T1 = *(const float2*)(T + (size_t)(b + 1) * FD + 2 * lane);
                float wx = fmaf(fr, T1.x - T0.x, T0.x) * msk;
                float wy = fmaf(fr, T1.y - T0.y, T0.y) * msk;
                ax = fmaf(tx, wx, ax);
                ay = fmaf(ty, wy, ay);
            }
        }
    }
    unsigned int o = (unsigned int)f2bf(ax) | ((unsigned int)f2bf(ay) << 16);
    *(unsigned int*)(agg + (size_t)i * FD + 2 * lane) = o;
}

// Readout, MFMA + fused epilogue: G1 = ssp(h@w_g1+b_g1); p = G1@w_g2+b_g2;
// atomicAdd(out[batch[row]], p). N=64 -> 4 col tiles. 34.8KB LDS, 4 blk/CU.
__global__ __launch_bounds__(256) void k_readout(const unsigned short* __restrict__ hb,
                                                 const int* __restrict__ batch,
                                                 const unsigned short* __restrict__ wg1T,
                                                 const float* __restrict__ b_g1,
                                                 const float* __restrict__ w_g2,
                                                 const float* __restrict__ b_g2,
                                                 float* __restrict__ out) {
    __shared__ unsigned short Als[64 * ASTR];
    __shared__ unsigned short Bls[64 * ASTR];
    int tx = threadIdx.x;
    int row0 = blockIdx.x * 64;
    #pragma unroll
    for (int q = 0; q < 4; ++q) {
        int l = tx + q * 256;
        int r = l >> 4, c = l & 15;
        int grow = row0 + r;
        uint4 v = make_uint4(0u, 0u, 0u, 0u);
        if (grow < NN) v = *(const uint4*)(hb + (size_t)grow * 128 + c * 8);
        *(uint4*)(&Als[r * ASTR + c * 8]) = v;
    }
    #pragma unroll
    for (int q = 0; q < 4; ++q) {
        int l = tx + q * 256;
        int r = l >> 4, c = l & 15;
        *(uint4*)(&Bls[r * ASTR + c * 8]) = *(const uint4*)(wg1T + (size_t)r * 128 + c * 8);
    }
    __syncthreads();

    int w = tx >> 6, lane = tx & 63;
    int m = lane & 15, quad = lane >> 4;
    f32x4 acc[4];
    #pragma unroll
    for (int ct = 0; ct < 4; ++ct) acc[ct] = (f32x4){0.f, 0.f, 0.f, 0.f};
    #pragma unroll
    for (int s = 0; s < 4; ++s) {
        bf16x8 a = *(const bf16x8*)(&Als[(w * 16 + m) * ASTR + s * 32 + quad * 8]);
        #pragma unroll
        for (int ct = 0; ct < 4; ++ct) {
            bf16x8 b = *(const bf16x8*)(&Bls[(ct * 16 + m) * ASTR + s * 32 + quad * 8]);
            acc[ct] = __builtin_amdgcn_mfma_f32_16x16x32_bf16(a, b, acc[ct], 0, 0, 0);
        }
    }
    float bg1[4], w2[4];
    #pragma unroll
    for (int ct = 0; ct < 4; ++ct) {
        int col = ct * 16 + m;
        bg1[ct] = b_g1[col];
        w2[ct]  = w_g2[col];
    }
    float bg2 = b_g2[0];
    #pragma unroll
    for (int r = 0; r < 4; ++r) {
        float p = 0.f;
        #pragma unroll
        for (int ct = 0; ct < 4; ++ct) p += sspf(acc[ct][r] + bg1[ct]) * w2[ct];
        p += __shfl_down(p, 8, 16);
        p += __shfl_down(p, 4, 16);
        p += __shfl_down(p, 2, 16);
        p += __shfl_down(p, 1, 16);
        if (m == 0) {
            int row = row0 + w * 16 + quad * 4 + r;
            if (row < NN) atomicAdd(&out[batch[row]], p + bg2);
        }
    }
}

extern "C" void kernel_launch(void* const* d_in, const int* in_sizes, int n_in,
                              void* d_out, int out_size, void* d_ws, size_t ws_size,
                              hipStream_t stream) {
    const int*   charges = (const int*)d_in[0];
    const float* coords  = (const float*)d_in[1];
    const int*   eidx    = (const int*)d_in[2];
    const int*   batch   = (const int*)d_in[3];
    const float* emb     = (const float*)d_in[4];
    const float* w_e1    = (const float*)d_in[5];
    const float* b_e1    = (const float*)d_in[6];
    const float* w_e2    = (const float*)d_in[7];
    const float* b_e2    = (const float*)d_in[8];
    const float* w_el    = (const float*)d_in[9];
    const float* w_nm    = (const float*)d_in[10];
    const float* b_nm    = (const float*)d_in[11];
    const float* w_g1    = (const float*)d_in[12];
    const float* b_g1    = (const float*)d_in[13];
    const float* w_g2    = (const float*)d_in[14];
    const float* b_g2    = (const float*)d_in[15];
    float* out = (float*)d_out;

    char* ws = (char*)d_ws;
    size_t off = 0;
    auto alloc = [&](size_t bytes) -> char* {
        char* p = ws + off;
        off += (bytes + 255) & ~(size_t)255;
        return p;
    };
    float*          h    = (float*)alloc((size_t)NN * HD * 4);          // 25.6 MB
    unsigned short* hb   = (unsigned short*)alloc((size_t)NN * HD * 2); // 12.8 MB
    unsigned short* t    = (unsigned short*)alloc((size_t)NN * FD * 2); // 12.8 MB
    unsigned short* aggb = (unsigned short*)alloc((size_t)NN * FD * 2); // 12.8 MB
    float*          T    = (float*)alloc((size_t)NB * FD * 4);          // 2 MB
    int*            deg  = (int*)alloc((size_t)NN * 4);                 // 0.2 MB
    int*            ecol = (int*)alloc((size_t)NN * ELLS * 4);          // 16 MB
    float*          ed   = (float*)alloc((size_t)NN * ELLS * 4);        // 16 MB
    unsigned short* welT = (unsigned short*)alloc((size_t)HD * FD * 2);
    unsigned short* wnmT = (unsigned short*)alloc((size_t)FD * HD * 2);
    unsigned short* wg1T = (unsigned short*)alloc((size_t)64 * HD * 2);
    if (off > ws_size) return;  // workspace too small -> fail visibly, no OOB

    hipMemsetAsync(deg, 0, (size_t)NN * 4, stream);
    hipMemsetAsync(out, 0, (size_t)NGR * 4, stream);

    k_embed<<<(NN * (HD / 4) + 255) / 256, 256, 0, stream>>>(charges, emb, h, hb);
    k_table<<<NB, 128, 0, stream>>>(w_e1, b_e1, w_e2, b_e2, T);
    k_edgeprep<<<(NE + 255) / 256, 256, 0, stream>>>(eidx, coords, deg, ecol, ed);
    k_ellpad<<<(NN + 255) / 256, 256, 0, stream>>>(deg, ecol, ed);
    k_prepw<<<(HD * FD + 255) / 256, 256, 0, stream>>>(w_el, welT, HD, FD);
    k_prepw<<<(FD * HD + 255) / 256, 256, 0, stream>>>(w_nm, wnmT, FD, HD);
    k_prepw<<<(HD * 64 + 255) / 256, 256, 0, stream>>>(w_g1, wg1T, HD, 64);

    for (int it = 0; it < 2; ++it) {
        // t = bf16(h @ w_el)
        k_gemm_mfma<<<(NN + 63) / 64, 256, 0, stream>>>(hb, welT, nullptr, nullptr,
                                                        nullptr, t, NN);
        k_agg<<<NN / 4, 256, 0, stream>>>(t, T, deg, ecol, ed, aggb);
        // h = h + agg @ w_nm + b_nm  (fp32 residual + bf16 shadow)
        k_gemm_mfma<<<(NN + 63) / 64, 256, 0, stream>>>(aggb, wnmT, h, b_nm,
                                                        h, hb, NN);
    }
    k_readout<<<(NN + 63) / 64, 256, 0, stream>>>(hb, batch, wg1T, b_g1, w_g2, b_g2, out);
}

// Round 5
// 409.159 us; speedup vs baseline: 1.5766x; 1.1279x over previous
//
#include <hip/hip_runtime.h>
#include <hip/hip_bf16.h>

// SchNet forward on MI355X.
// W(d) depends only on scalar d -> 1024-bin lookup table (lerp, 6-bit frac),
// ELL bucketing by destination row for atomic-free segment sum, bf16 MFMA for
// all 128-wide GEMMs (fp32 residual stream), fused readout epilogue.
// R5: k_agg was ds-pipe/instruction bound (4 shfl + 3 vmem per edge).
//     Now: packed 32-bit edge meta (1 shfl), interleaved table pairs (1x16B
//     load), zero-row sentinel (no mask, no ed array).

#define NN 50000      // nodes
#define NE 800000     // edges
#define NGR 512       // graphs
#define HD 128        // hidden
#define FD 128        // filters
#define GG 50         // gaussians
#define NB 1024       // table bins (10 bits)
#define DMAXT 12.0f   // table covers [0,12]; beyond, W const (gauss < e^-48)
#define ELLS 80       // ELL stride (multiple of 8); deg ~ Poisson(16)
#define ASTR 136      // LDS row stride in bf16 elems (128+8)
#define SENT 50000u   // sentinel col -> zeroed extra row of t

#define DELTA (10.0f/49.0f)
#define COEFF (-0.5f/(DELTA*DELTA))

typedef __attribute__((ext_vector_type(8))) short bf16x8;
typedef __attribute__((ext_vector_type(4))) float f32x4;

static __device__ __forceinline__ float sspf(float x) {
    return fmaxf(x, 0.0f) + log1pf(expf(-fabsf(x))) - 0.69314718055994531f;
}
static __device__ __forceinline__ float bf2f(unsigned short b) {
    union { unsigned int u; float f; } v; v.u = ((unsigned int)b) << 16; return v.f;
}
static __device__ __forceinline__ unsigned short f2bf(float f) {
    union { float f; unsigned int u; } v; v.f = f;
    unsigned int r = v.u + 0x7FFF + ((v.u >> 16) & 1);   // round-nearest-even
    return (unsigned short)(r >> 16);
}

// h[i,:] = emb[charges[i],:]  fp32 + bf16 shadow
__global__ __launch_bounds__(256) void k_embed(const int* __restrict__ charges,
                                               const float* __restrict__ emb,
                                               float* __restrict__ h,
                                               unsigned short* __restrict__ hb) {
    int idx = blockIdx.x * blockDim.x + threadIdx.x;   // over NN*32 float4s
    if (idx >= NN * (HD / 4)) return;
    int i  = idx >> 5;
    int f4 = idx & 31;
    float4 v = ((const float4*)emb)[charges[i] * (HD / 4) + f4];
    ((float4*)h)[idx] = v;
    ushort4 o;
    o.x = f2bf(v.x); o.y = f2bf(v.y); o.z = f2bf(v.z); o.w = f2bf(v.w);
    *(ushort4*)(hb + (size_t)idx * 4) = o;
}

// Build table T[b,:] = ssp(gauss(d_b)@w_e1 + b_e1)@w_e2 + b_e2
__global__ __launch_bounds__(128) void k_table(const float* __restrict__ w_e1,
                                               const float* __restrict__ b_e1,
                                               const float* __restrict__ w_e2,
                                               const float* __restrict__ b_e2,
                                               float* __restrict__ T) {
    __shared__ float a[GG];
    __shared__ float y[FD];
    int b = blockIdx.x;
    int f = threadIdx.x;
    float d = (float)b * (DMAXT / (float)(NB - 1));
    if (f < GG) {
        float off = (float)f * DELTA;
        float t = d - off;
        a[f] = expf(COEFF * t * t);
    }
    __syncthreads();
    float acc = b_e1[f];
    #pragma unroll 10
    for (int g = 0; g < GG; ++g) acc = fmaf(a[g], w_e1[g * FD + f], acc);
    y[f] = sspf(acc);
    __syncthreads();
    float acc2 = b_e2[f];
    #pragma unroll 8
    for (int k = 0; k < FD; ++k) acc2 = fmaf(y[k], w_e2[k * FD + f], acc2);
    T[b * FD + f] = acc2;
}

// Interleave adjacent table rows: Tp[b][lane] = (T[b][2l], T[b][2l+1],
// T[b+1][2l], T[b+1][2l+1]) so lerp needs one 16B load.
__global__ __launch_bounds__(256) void k_tpair(const float* __restrict__ T,
                                               float* __restrict__ Tp) {
    int idx = blockIdx.x * blockDim.x + threadIdx.x;   // over (NB-1)*64
    if (idx >= (NB - 1) * 64) return;
    int b = idx >> 6, l = idx & 63;
    float2 a = *(const float2*)(T + (size_t)b * FD + 2 * l);
    float2 c = *(const float2*)(T + (size_t)(b + 1) * FD + 2 * l);
    float4 v = make_float4(a.x, a.y, c.x, c.y);
    ((float4*)Tp)[idx] = v;
}

// wT[n*K+k] = bf16(w[k*N+n])
__global__ __launch_bounds__(256) void k_prepw(const float* __restrict__ w,
                                               unsigned short* __restrict__ wT,
                                               int K, int N) {
    int idx = blockIdx.x * blockDim.x + threadIdx.x;
    if (idx >= K * N) return;
    int n = idx / K, k = idx - n * K;
    wT[idx] = f2bf(w[k * N + n]);
}

// Per edge: pack (col 16b | bin 10b | frac6 6b) into ELL slot of row.
__global__ __launch_bounds__(256) void k_edgeprep(const int* __restrict__ eidx,
                                                  const float* __restrict__ coords,
                                                  int* __restrict__ deg,
                                                  unsigned int* __restrict__ emll) {
    int e = blockIdx.x * blockDim.x + threadIdx.x;
    if (e >= NE) return;
    int r = eidx[e];
    int c = eidx[NE + e];
    float dx = coords[r * 3 + 0] - coords[c * 3 + 0];
    float dy = coords[r * 3 + 1] - coords[c * 3 + 1];
    float dz = coords[r * 3 + 2] - coords[c * 3 + 2];
    float d = sqrtf(dx * dx + dy * dy + dz * dz);
    float u = fminf(d * ((float)(NB - 1) / DMAXT), (float)(NB - 2) + 0.9999f);
    int b = (int)u;                       // <= NB-2
    int fr6 = (int)((u - (float)b) * 64.0f);  // 0..63
    unsigned int em = (unsigned int)c | ((unsigned int)b << 16)
                    | ((unsigned int)fr6 << 26);
    int pos = atomicAdd(&deg[r], 1);
    if (pos < ELLS) emll[r * ELLS + pos] = em;
}

// Pad each ELL row up to a multiple of 8 with sentinel (col=SENT -> t row is 0).
__global__ __launch_bounds__(256) void k_ellpad(const int* __restrict__ deg,
                                                unsigned int* __restrict__ emll) {
    int i = blockIdx.x * blockDim.x + threadIdx.x;
    if (i >= NN) return;
    int dg = min(deg[i], ELLS);
    int dgp = (dg + 7) & ~7;
    for (int j = dg; j < dgp; ++j) emll[i * ELLS + j] = SENT;
}

// MFMA GEMM: C[M,128] = A[M,128](bf16) @ BT[128,128]^T(bf16) (+Cin)(+bias).
__global__ __launch_bounds__(256) void k_gemm_mfma(const unsigned short* __restrict__ A,
                                                   const unsigned short* __restrict__ BT,
                                                   const float* __restrict__ Cin,
                                                   const float* __restrict__ bias,
                                                   float* __restrict__ Cout,
                                                   unsigned short* __restrict__ Cout16,
                                                   int M) {
    __shared__ unsigned short Als[64 * ASTR];    // 17.4 KB
    __shared__ unsigned short Bls[128 * ASTR];   // 34.8 KB
    int tx = threadIdx.x;
    int row0 = blockIdx.x * 64;
    #pragma unroll
    for (int q = 0; q < 4; ++q) {            // A: 64 rows x 16 chunks of 16B
        int l = tx + q * 256;
        int r = l >> 4, c = l & 15;
        int grow = row0 + r;
        uint4 v = make_uint4(0u, 0u, 0u, 0u);
        if (grow < M) v = *(const uint4*)(A + (size_t)grow * 128 + c * 8);
        *(uint4*)(&Als[r * ASTR + c * 8]) = v;
    }
    #pragma unroll
    for (int q = 0; q < 8; ++q) {            // BT: 128 rows x 16 chunks
        int l = tx + q * 256;
        int r = l >> 4, c = l & 15;
        *(uint4*)(&Bls[r * ASTR + c * 8]) = *(const uint4*)(BT + (size_t)r * 128 + c * 8);
    }
    __syncthreads();

    int w = tx >> 6, lane = tx & 63;
    int m = lane & 15, quad = lane >> 4;
    f32x4 acc[8];
    #pragma unroll
    for (int ct = 0; ct < 8; ++ct) acc[ct] = (f32x4){0.f, 0.f, 0.f, 0.f};
    #pragma unroll
    for (int s = 0; s < 4; ++s) {
        bf16x8 a = *(const bf16x8*)(&Als[(w * 16 + m) * ASTR + s * 32 + quad * 8]);
        #pragma unroll
        for (int ct = 0; ct < 8; ++ct) {
            bf16x8 b = *(const bf16x8*)(&Bls[(ct * 16 + m) * ASTR + s * 32 + quad * 8]);
            acc[ct] = __builtin_amdgcn_mfma_f32_16x16x32_bf16(a, b, acc[ct], 0, 0, 0);
        }
    }
    #pragma unroll
    for (int r = 0; r < 4; ++r) {
        int grow = row0 + w * 16 + quad * 4 + r;
        if (grow >= M) continue;
        #pragma unroll
        for (int ct = 0; ct < 8; ++ct) {
            int col = ct * 16 + m;
            float v = acc[ct][r];
            if (bias) v += bias[col];
            if (Cin)  v += Cin[(size_t)grow * 128 + col];
            if (Cout)   Cout[(size_t)grow * 128 + col] = v;
            if (Cout16) Cout16[(size_t)grow * 128 + col] = f2bf(v);
        }
    }
}

// One wave per node: agg[i,:] = sum_j t[col_j,:] * lerp(Tp, em_j).
// Per edge: 1 shfl + 1x4B t load + 1x16B Tp load.
__global__ __launch_bounds__(256) void k_agg(const unsigned short* __restrict__ t,
                                             const float* __restrict__ Tp,
                                             const int* __restrict__ deg,
                                             const unsigned int* __restrict__ emll,
                                             unsigned short* __restrict__ agg) {
    int wave = (blockIdx.x * blockDim.x + threadIdx.x) >> 6;
    int lane = threadIdx.x & 63;
    if (wave >= NN) return;
    int dg = min(deg[wave], ELLS);
    int dgp = (dg + 7) & ~7;
    const int base = wave * ELLS;
    float ax = 0.f, ay = 0.f;
    for (int j0 = 0; j0 < dgp; j0 += 64) {
        int n = min(64, dgp - j0);
        unsigned int myem = SENT;
        if (lane < n) myem = emll[base + j0 + lane];
        for (int j = 0; j < n; j += 8) {
            #pragma unroll
            for (int u = 0; u < 8; ++u) {
                unsigned int em = (unsigned int)__shfl((int)myem, j + u, 64);
                int c  = em & 0xFFFF;
                int b  = (em >> 16) & 0x3FF;
                float fr = (float)(em >> 26) * (1.0f / 64.0f);
                unsigned int tv = *(const unsigned int*)(t + (size_t)c * HD + 2 * lane);
                float4 Tq = *(const float4*)(Tp + ((size_t)b * 64 + lane) * 4);
                float wx = fmaf(fr, Tq.z - Tq.x, Tq.x);
                float wy = fmaf(fr, Tq.w - Tq.y, Tq.y);
                ax = fmaf(bf2f((unsigned short)(tv & 0xFFFFu)), wx, ax);
                ay = fmaf(bf2f((unsigned short)(tv >> 16)), wy, ay);
            }
        }
    }
    unsigned int o = (unsigned int)f2bf(ax) | ((unsigned int)f2bf(ay) << 16);
    *(unsigned int*)(agg + (size_t)wave * FD + 2 * lane) = o;
}

// Readout, MFMA + fused epilogue: p = ssp(h@w_g1+b_g1)@w_g2 + b_g2,
// atomicAdd(out[batch[row]], p).
__global__ __launch_bounds__(256) void k_readout(const unsigned short* __restrict__ hb,
                                                 const int* __restrict__ batch,
                                                 const unsigned short* __restrict__ wg1T,
                                                 const float* __restrict__ b_g1,
                                                 const float* __restrict__ w_g2,
                                                 const float* __restrict__ b_g2,
                                                 float* __restrict__ out) {
    __shared__ unsigned short Als[64 * ASTR];
    __shared__ unsigned short Bls[64 * ASTR];
    int tx = threadIdx.x;
    int row0 = blockIdx.x * 64;
    #pragma unroll
    for (int q = 0; q < 4; ++q) {
        int l = tx + q * 256;
        int r = l >> 4, c = l & 15;
        int grow = row0 + r;
        uint4 v = make_uint4(0u, 0u, 0u, 0u);
        if (grow < NN) v = *(const uint4*)(hb + (size_t)grow * 128 + c * 8);
        *(uint4*)(&Als[r * ASTR + c * 8]) = v;
    }
    #pragma unroll
    for (int q = 0; q < 4; ++q) {
        int l = tx + q * 256;
        int r = l >> 4, c = l & 15;
        *(uint4*)(&Bls[r * ASTR + c * 8]) = *(const uint4*)(wg1T + (size_t)r * 128 + c * 8);
    }
    __syncthreads();

    int w = tx >> 6, lane = tx & 63;
    int m = lane & 15, quad = lane >> 4;
    f32x4 acc[4];
    #pragma unroll
    for (int ct = 0; ct < 4; ++ct) acc[ct] = (f32x4){0.f, 0.f, 0.f, 0.f};
    #pragma unroll
    for (int s = 0; s < 4; ++s) {
        bf16x8 a = *(const bf16x8*)(&Als[(w * 16 + m) * ASTR + s * 32 + quad * 8]);
        #pragma unroll
        for (int ct = 0; ct < 4; ++ct) {
            bf16x8 b = *(const bf16x8*)(&Bls[(ct * 16 + m) * ASTR + s * 32 + quad * 8]);
            acc[ct] = __builtin_amdgcn_mfma_f32_16x16x32_bf16(a, b, acc[ct], 0, 0, 0);
        }
    }
    float bg1[4], w2[4];
    #pragma unroll
    for (int ct = 0; ct < 4; ++ct) {
        int col = ct * 16 + m;
        bg1[ct] = b_g1[col];
        w2[ct]  = w_g2[col];
    }
    float bg2 = b_g2[0];
    #pragma unroll
    for (int r = 0; r < 4; ++r) {
        float p = 0.f;
        #pragma unroll
        for (int ct = 0; ct < 4; ++ct) p += sspf(acc[ct][r] + bg1[ct]) * w2[ct];
        p += __shfl_down(p, 8, 16);
        p += __shfl_down(p, 4, 16);
        p += __shfl_down(p, 2, 16);
        p += __shfl_down(p, 1, 16);
        if (m == 0) {
            int row = row0 + w * 16 + quad * 4 + r;
            if (row < NN) atomicAdd(&out[batch[row]], p + bg2);
        }
    }
}

extern "C" void kernel_launch(void* const* d_in, const int* in_sizes, int n_in,
                              void* d_out, int out_size, void* d_ws, size_t ws_size,
                              hipStream_t stream) {
    const int*   charges = (const int*)d_in[0];
    const float* coords  = (const float*)d_in[1];
    const int*   eidx    = (const int*)d_in[2];
    const int*   batch   = (const int*)d_in[3];
    const float* emb     = (const float*)d_in[4];
    const float* w_e1    = (const float*)d_in[5];
    const float* b_e1    = (const float*)d_in[6];
    const float* w_e2    = (const float*)d_in[7];
    const float* b_e2    = (const float*)d_in[8];
    const float* w_el    = (const float*)d_in[9];
    const float* w_nm    = (const float*)d_in[10];
    const float* b_nm    = (const float*)d_in[11];
    const float* w_g1    = (const float*)d_in[12];
    const float* b_g1    = (const float*)d_in[13];
    const float* w_g2    = (const float*)d_in[14];
    const float* b_g2    = (const float*)d_in[15];
    float* out = (float*)d_out;

    char* ws = (char*)d_ws;
    size_t off = 0;
    auto alloc = [&](size_t bytes) -> char* {
        char* p = ws + off;
        off += (bytes + 255) & ~(size_t)255;
        return p;
    };
    float*          h    = (float*)alloc((size_t)NN * HD * 4);               // 25.6 MB
    unsigned short* hb   = (unsigned short*)alloc((size_t)NN * HD * 2);      // 12.8 MB
    unsigned short* t    = (unsigned short*)alloc((size_t)(NN + 1) * HD * 2);// 12.8 MB (+1 sentinel row)
    unsigned short* aggb = (unsigned short*)alloc((size_t)NN * FD * 2);      // 12.8 MB
    float*          T    = (float*)alloc((size_t)NB * FD * 4);               // 0.5 MB
    float*          Tp   = (float*)alloc((size_t)NB * 64 * 4 * 4);           // 1 MB
    int*            deg  = (int*)alloc((size_t)NN * 4);                      // 0.2 MB
    unsigned int*   emll = (unsigned int*)alloc((size_t)NN * ELLS * 4);      // 16 MB
    unsigned short* welT = (unsigned short*)alloc((size_t)HD * FD * 2);
    unsigned short* wnmT = (unsigned short*)alloc((size_t)FD * HD * 2);
    unsigned short* wg1T = (unsigned short*)alloc((size_t)64 * HD * 2);
    if (off > ws_size) return;  // workspace too small -> fail visibly, no OOB

    hipMemsetAsync(deg, 0, (size_t)NN * 4, stream);
    hipMemsetAsync(out, 0, (size_t)NGR * 4, stream);
    hipMemsetAsync(t + (size_t)NN * HD, 0, HD * 2, stream);   // sentinel row = 0

    k_embed<<<(NN * (HD / 4) + 255) / 256, 256, 0, stream>>>(charges, emb, h, hb);
    k_table<<<NB, 128, 0, stream>>>(w_e1, b_e1, w_e2, b_e2, T);
    k_tpair<<<((NB - 1) * 64 + 255) / 256, 256, 0, stream>>>(T, Tp);
    k_edgeprep<<<(NE + 255) / 256, 256, 0, stream>>>(eidx, coords, deg, emll);
    k_ellpad<<<(NN + 255) / 256, 256, 0, stream>>>(deg, emll);
    k_prepw<<<(HD * FD + 255) / 256, 256, 0, stream>>>(w_el, welT, HD, FD);
    k_prepw<<<(FD * HD + 255) / 256, 256, 0, stream>>>(w_nm, wnmT, FD, HD);
    k_prepw<<<(HD * 64 + 255) / 256, 256, 0, stream>>>(w_g1, wg1T, HD, 64);

    for (int it = 0; it < 2; ++it) {
        // t = bf16(h @ w_el)
        k_gemm_mfma<<<(NN + 63) / 64, 256, 0, stream>>>(hb, welT, nullptr, nullptr,
                                                        nullptr, t, NN);
        k_agg<<<NN / 4, 256, 0, stream>>>(t, Tp, deg, emll, aggb);
        // h = h + agg @ w_nm + b_nm  (fp32 residual + bf16 shadow)
        k_gemm_mfma<<<(NN + 63) / 64, 256, 0, stream>>>(aggb, wnmT, h, b_nm,
                                                        h, hb, NN);
    }
    k_readout<<<(NN + 63) / 64, 256, 0, stream>>>(hb, batch, wg1T, b_g1, w_g2, b_g2, out);
}

// Round 6
// 354.816 us; speedup vs baseline: 1.8181x; 1.1532x over previous
//
#include <hip/hip_runtime.h>
#include <hip/hip_bf16.h>

// SchNet forward on MI355X.
// W(d) depends only on scalar d -> 1024-bin bf16 (T0,dT) lookup table, ELL
// bucketing (packed 32-bit edge meta) for atomic-free segment sum, bf16 MFMA
// GEMMs (fp32 residual stream), fused readout epilogue.
// R6: (a) t1 = (emb@w_el)[charges] vocab trick kills one 50k GEMM;
//     (b) GEMMs: 512-thr / 128-row tiles -> 2 blk/CU, 50% occupancy, half
//         the B re-staging; last update skips fp32 h write;
//     (c) k_agg table in bf16 (T0,dT): per-edge table load 16B->8B.

#define NN 50000      // nodes
#define NE 800000     // edges
#define NGR 512       // graphs
#define HD 128        // hidden
#define FD 128        // filters
#define GG 50         // gaussians
#define NB 1024       // table bins (10 bits)
#define DMAXT 12.0f   // table covers [0,12]; beyond, W const (gauss < e^-48)
#define ELLS 80       // ELL stride (multiple of 8); deg ~ Poisson(16)
#define ASTR 136      // LDS row stride in bf16 elems (128+8)
#define SENT 50000u   // sentinel col -> zeroed extra row of t

#define DELTA (10.0f/49.0f)
#define COEFF (-0.5f/(DELTA*DELTA))

typedef __attribute__((ext_vector_type(8))) short bf16x8;
typedef __attribute__((ext_vector_type(4))) float f32x4;

static __device__ __forceinline__ float sspf(float x) {
    return fmaxf(x, 0.0f) + log1pf(expf(-fabsf(x))) - 0.69314718055994531f;
}
static __device__ __forceinline__ float asf(unsigned int u) {
    union { unsigned int u; float f; } v; v.u = u; return v.f;
}
static __device__ __forceinline__ unsigned short f2bf(float f) {
    union { float f; unsigned int u; } v; v.f = f;
    unsigned int r = v.u + 0x7FFF + ((v.u >> 16) & 1);   // round-nearest-even
    return (unsigned short)(r >> 16);
}

// tv = emb @ w_el  (100x128 fp32 -> bf16), one block per vocab row
__global__ __launch_bounds__(128) void k_tv(const float* __restrict__ emb,
                                            const float* __restrict__ w_el,
                                            unsigned short* __restrict__ tv) {
    __shared__ float er[HD];
    int r = blockIdx.x, n = threadIdx.x;
    er[n] = emb[r * HD + n];
    __syncthreads();
    float acc = 0.f;
    #pragma unroll 8
    for (int k = 0; k < HD; ++k) acc = fmaf(er[k], w_el[k * FD + n], acc);
    tv[r * FD + n] = f2bf(acc);
}

// h[i,:] = emb[charges[i],:] (fp32); t[i,:] = tv[charges[i],:] (bf16)
__global__ __launch_bounds__(256) void k_embed(const int* __restrict__ charges,
                                               const float* __restrict__ emb,
                                               const unsigned short* __restrict__ tv,
                                               float* __restrict__ h,
                                               unsigned short* __restrict__ t) {
    int idx = blockIdx.x * blockDim.x + threadIdx.x;   // over NN*32 float4s
    if (idx >= NN * (HD / 4)) return;
    int i  = idx >> 5;
    int f4 = idx & 31;
    int c = charges[i];
    ((float4*)h)[idx] = ((const float4*)emb)[c * (HD / 4) + f4];
    *(ushort4*)(t + (size_t)i * HD + f4 * 4) =
        *(const ushort4*)(tv + (size_t)c * HD + f4 * 4);
}

// Build table T[b,:] = ssp(gauss(d_b)@w_e1 + b_e1)@w_e2 + b_e2
__global__ __launch_bounds__(128) void k_table(const float* __restrict__ w_e1,
                                               const float* __restrict__ b_e1,
                                               const float* __restrict__ w_e2,
                                               const float* __restrict__ b_e2,
                                               float* __restrict__ T) {
    __shared__ float a[GG];
    __shared__ float y[FD];
    int b = blockIdx.x;
    int f = threadIdx.x;
    float d = (float)b * (DMAXT / (float)(NB - 1));
    if (f < GG) {
        float off = (float)f * DELTA;
        float tt = d - off;
        a[f] = expf(COEFF * tt * tt);
    }
    __syncthreads();
    float acc = b_e1[f];
    #pragma unroll 10
    for (int g = 0; g < GG; ++g) acc = fmaf(a[g], w_e1[g * FD + f], acc);
    y[f] = sspf(acc);
    __syncthreads();
    float acc2 = b_e2[f];
    #pragma unroll 8
    for (int k = 0; k < FD; ++k) acc2 = fmaf(y[k], w_e2[k * FD + f], acc2);
    T[b * FD + f] = acc2;
}

// Tpb[b*64+l] = uint2{ bf(T[b][2l]) | bf(T[b][2l+1])<<16,
//                      bf(dT[2l])   | bf(dT[2l+1])<<16 },  dT = T[b+1]-T[b]
__global__ __launch_bounds__(256) void k_tpair(const float* __restrict__ T,
                                               uint2* __restrict__ Tpb) {
    int idx = blockIdx.x * blockDim.x + threadIdx.x;   // over (NB-1)*64
    if (idx >= (NB - 1) * 64) return;
    int b = idx >> 6, l = idx & 63;
    float2 a = *(const float2*)(T + (size_t)b * FD + 2 * l);
    float2 c = *(const float2*)(T + (size_t)(b + 1) * FD + 2 * l);
    uint2 o;
    o.x = (unsigned int)f2bf(a.x) | ((unsigned int)f2bf(a.y) << 16);
    o.y = (unsigned int)f2bf(c.x - a.x) | ((unsigned int)f2bf(c.y - a.y) << 16);
    Tpb[idx] = o;
}

// Fused weight transposes: welT(128x128), wnmT(128x128), wg1T(64x128)
__global__ __launch_bounds__(256) void k_prepw(const float* __restrict__ w_el,
                                               const float* __restrict__ w_nm,
                                               const float* __restrict__ w_g1,
                                               unsigned short* __restrict__ welT,
                                               unsigned short* __restrict__ wnmT,
                                               unsigned short* __restrict__ wg1T) {
    int idx = blockIdx.x * blockDim.x + threadIdx.x;
    if (idx < 16384) {                       // welT[n*128+k] = w_el[k*128+n]
        int n = idx >> 7, k = idx & 127;
        welT[idx] = f2bf(w_el[k * 128 + n]);
    } else if (idx < 32768) {                // wnmT
        int j = idx - 16384;
        int n = j >> 7, k = j & 127;
        wnmT[j] = f2bf(w_nm[k * 128 + n]);
    } else if (idx < 40960) {                // wg1T[n*128+k] = w_g1[k*64+n]
        int j = idx - 32768;
        int n = j >> 7, k = j & 127;
        wg1T[j] = f2bf(w_g1[k * 64 + n]);
    }
}

// Per edge: pack (col 16b | bin 10b | frac6 6b) into ELL slot of row.
__global__ __launch_bounds__(256) void k_edgeprep(const int* __restrict__ eidx,
                                                  const float* __restrict__ coords,
                                                  int* __restrict__ deg,
                                                  unsigned int* __restrict__ emll) {
    int e = blockIdx.x * blockDim.x + threadIdx.x;
    if (e >= NE) return;
    int r = eidx[e];
    int c = eidx[NE + e];
    float dx = coords[r * 3 + 0] - coords[c * 3 + 0];
    float dy = coords[r * 3 + 1] - coords[c * 3 + 1];
    float dz = coords[r * 3 + 2] - coords[c * 3 + 2];
    float d = sqrtf(dx * dx + dy * dy + dz * dz);
    float u = fminf(d * ((float)(NB - 1) / DMAXT), (float)(NB - 2) + 0.9999f);
    int b = (int)u;
    int fr6 = (int)((u - (float)b) * 64.0f);
    unsigned int em = (unsigned int)c | ((unsigned int)b << 16)
                    | ((unsigned int)fr6 << 26);
    int pos = atomicAdd(&deg[r], 1);
    if (pos < ELLS) emll[r * ELLS + pos] = em;
}

// Pad each ELL row up to a multiple of 8 with sentinel (col=SENT -> t row 0).
__global__ __launch_bounds__(256) void k_ellpad(const int* __restrict__ deg,
                                                unsigned int* __restrict__ emll) {
    int i = blockIdx.x * blockDim.x + threadIdx.x;
    if (i >= NN) return;
    int dg = min(deg[i], ELLS);
    int dgp = (dg + 7) & ~7;
    for (int j = dg; j < dgp; ++j) emll[i * ELLS + j] = SENT;
}

// MFMA GEMM, 512 threads, 128-row tiles: C = A(bf16) @ BT^T (+Cin)(+bias).
// LDS 69.6KB -> 2 blocks/CU (16 waves). Wave w: rows 16w..16w+15 x 128 cols.
__global__ __launch_bounds__(512, 4) void k_gemm_mfma(const unsigned short* __restrict__ A,
                                                      const unsigned short* __restrict__ BT,
                                                      const float* __restrict__ Cin,
                                                      const float* __restrict__ bias,
                                                      float* __restrict__ Cout,
                                                      unsigned short* __restrict__ Cout16,
                                                      int M) {
    __shared__ unsigned short Als[128 * ASTR];   // 34.8 KB
    __shared__ unsigned short Bls[128 * ASTR];   // 34.8 KB
    int tx = threadIdx.x;
    int row0 = blockIdx.x * 128;
    #pragma unroll
    for (int q = 0; q < 4; ++q) {            // A: 128 rows x 16 chunks of 8 bf16
        int l = tx + q * 512;
        int r = l >> 4, c = l & 15;
        int grow = row0 + r;
        uint4 v = make_uint4(0u, 0u, 0u, 0u);
        if (grow < M) v = *(const uint4*)(A + (size_t)grow * 128 + c * 8);
        *(uint4*)(&Als[r * ASTR + c * 8]) = v;
    }
    #pragma unroll
    for (int q = 0; q < 4; ++q) {            // BT: 128 rows x 16 chunks
        int l = tx + q * 512;
        int r = l >> 4, c = l & 15;
        *(uint4*)(&Bls[r * ASTR + c * 8]) = *(const uint4*)(BT + (size_t)r * 128 + c * 8);
    }
    __syncthreads();

    int w = tx >> 6, lane = tx & 63;
    int m = lane & 15, quad = lane >> 4;
    f32x4 acc[8];
    #pragma unroll
    for (int ct = 0; ct < 8; ++ct) acc[ct] = (f32x4){0.f, 0.f, 0.f, 0.f};
    #pragma unroll
    for (int s = 0; s < 4; ++s) {
        bf16x8 a = *(const bf16x8*)(&Als[(w * 16 + m) * ASTR + s * 32 + quad * 8]);
        #pragma unroll
        for (int ct = 0; ct < 8; ++ct) {
            bf16x8 b = *(const bf16x8*)(&Bls[(ct * 16 + m) * ASTR + s * 32 + quad * 8]);
            acc[ct] = __builtin_amdgcn_mfma_f32_16x16x32_bf16(a, b, acc[ct], 0, 0, 0);
        }
    }
    #pragma unroll
    for (int r = 0; r < 4; ++r) {
        int grow = row0 + w * 16 + quad * 4 + r;
        if (grow >= M) continue;
        #pragma unroll
        for (int ct = 0; ct < 8; ++ct) {
            int col = ct * 16 + m;
            float v = acc[ct][r];
            if (bias) v += bias[col];
            if (Cin)  v += Cin[(size_t)grow * 128 + col];
            if (Cout)   Cout[(size_t)grow * 128 + col] = v;
            if (Cout16) Cout16[(size_t)grow * 128 + col] = f2bf(v);
        }
    }
}

// One wave per node: agg[i,:] = sum_j t[col_j,:] * lerp(Tpb, em_j).
// Per edge: 1 shfl + 4B t load + 8B table load + ~16 VALU.
__global__ __launch_bounds__(256) void k_agg(const unsigned short* __restrict__ t,
                                             const uint2* __restrict__ Tpb,
                                             const int* __restrict__ deg,
                                             const unsigned int* __restrict__ emll,
                                             unsigned short* __restrict__ agg) {
    int wave = (blockIdx.x * blockDim.x + threadIdx.x) >> 6;
    int lane = threadIdx.x & 63;
    if (wave >= NN) return;
    int dg = min(deg[wave], ELLS);
    int dgp = (dg + 7) & ~7;
    const int base = wave * ELLS;
    float ax = 0.f, ay = 0.f;
    for (int j0 = 0; j0 < dgp; j0 += 64) {
        int n = min(64, dgp - j0);
        unsigned int myem = SENT;
        if (lane < n) myem = emll[base + j0 + lane];
        for (int j = 0; j < n; j += 8) {
            #pragma unroll
            for (int u = 0; u < 8; ++u) {
                unsigned int em = (unsigned int)__shfl((int)myem, j + u, 64);
                int c  = em & 0xFFFF;
                int b  = (em >> 16) & 0x3FF;
                float fr = (float)(em >> 26) * (1.0f / 64.0f);
                unsigned int tv = *(const unsigned int*)(t + (size_t)c * HD + 2 * lane);
                uint2 q = Tpb[(size_t)b * 64 + lane];
                float wx = fmaf(fr, asf(q.y << 16), asf(q.x << 16));
                float wy = fmaf(fr, asf(q.y & 0xFFFF0000u), asf(q.x & 0xFFFF0000u));
                ax = fmaf(asf(tv << 16), wx, ax);
                ay = fmaf(asf(tv & 0xFFFF0000u), wy, ay);
            }
        }
    }
    unsigned int o = (unsigned int)f2bf(ax) | ((unsigned int)f2bf(ay) << 16);
    *(unsigned int*)(agg + (size_t)wave * FD + 2 * lane) = o;
}

// Readout, 512 threads / 128-row tiles: p = ssp(h@w_g1+b_g1)@w_g2 + b_g2,
// atomicAdd(out[batch[row]], p). LDS 52.2KB -> 3 blocks/CU.
__global__ __launch_bounds__(512, 4) void k_readout(const unsigned short* __restrict__ hb,
                                                    const int* __restrict__ batch,
                                                    const unsigned short* __restrict__ wg1T,
                                                    const float* __restrict__ b_g1,
                                                    const float* __restrict__ w_g2,
                                                    const float* __restrict__ b_g2,
                                                    float* __restrict__ out) {
    __shared__ unsigned short Als[128 * ASTR];   // 34.8 KB
    __shared__ unsigned short Bls[64 * ASTR];    // 17.4 KB
    int tx = threadIdx.x;
    int row0 = blockIdx.x * 128;
    #pragma unroll
    for (int q = 0; q < 4; ++q) {
        int l = tx + q * 512;
        int r = l >> 4, c = l & 15;
        int grow = row0 + r;
        uint4 v = make_uint4(0u, 0u, 0u, 0u);
        if (grow < NN) v = *(const uint4*)(hb + (size_t)grow * 128 + c * 8);
        *(uint4*)(&Als[r * ASTR + c * 8]) = v;
    }
    #pragma unroll
    for (int q = 0; q < 2; ++q) {
        int l = tx + q * 512;                // 0..1023: 64 rows x 16 chunks
        int r = l >> 4, c = l & 15;
        *(uint4*)(&Bls[r * ASTR + c * 8]) = *(const uint4*)(wg1T + (size_t)r * 128 + c * 8);
    }
    __syncthreads();

    int w = tx >> 6, lane = tx & 63;
    int m = lane & 15, quad = lane >> 4;
    f32x4 acc[4];
    #pragma unroll
    for (int ct = 0; ct < 4; ++ct) acc[ct] = (f32x4){0.f, 0.f, 0.f, 0.f};
    #pragma unroll
    for (int s = 0; s < 4; ++s) {
        bf16x8 a = *(const bf16x8*)(&Als[(w * 16 + m) * ASTR + s * 32 + quad * 8]);
        #pragma unroll
        for (int ct = 0; ct < 4; ++ct) {
            bf16x8 b = *(const bf16x8*)(&Bls[(ct * 16 + m) * ASTR + s * 32 + quad * 8]);
            acc[ct] = __builtin_amdgcn_mfma_f32_16x16x32_bf16(a, b, acc[ct], 0, 0, 0);
        }
    }
    float bg1[4], w2[4];
    #pragma unroll
    for (int ct = 0; ct < 4; ++ct) {
        int col = ct * 16 + m;
        bg1[ct] = b_g1[col];
        w2[ct]  = w_g2[col];
    }
    float bg2 = b_g2[0];
    #pragma unroll
    for (int r = 0; r < 4; ++r) {
        float p = 0.f;
        #pragma unroll
        for (int ct = 0; ct < 4; ++ct) p += sspf(acc[ct][r] + bg1[ct]) * w2[ct];
        p += __shfl_down(p, 8, 16);
        p += __shfl_down(p, 4, 16);
        p += __shfl_down(p, 2, 16);
        p += __shfl_down(p, 1, 16);
        if (m == 0) {
            int row = row0 + w * 16 + quad * 4 + r;
            if (row < NN) atomicAdd(&out[batch[row]], p + bg2);
        }
    }
}

extern "C" void kernel_launch(void* const* d_in, const int* in_sizes, int n_in,
                              void* d_out, int out_size, void* d_ws, size_t ws_size,
                              hipStream_t stream) {
    const int*   charges = (const int*)d_in[0];
    const float* coords  = (const float*)d_in[1];
    const int*   eidx    = (const int*)d_in[2];
    const int*   batch   = (const int*)d_in[3];
    const float* emb     = (const float*)d_in[4];
    const float* w_e1    = (const float*)d_in[5];
    const float* b_e1    = (const float*)d_in[6];
    const float* w_e2    = (const float*)d_in[7];
    const float* b_e2    = (const float*)d_in[8];
    const float* w_el    = (const float*)d_in[9];
    const float* w_nm    = (const float*)d_in[10];
    const float* b_nm    = (const float*)d_in[11];
    const float* w_g1    = (const float*)d_in[12];
    const float* b_g1    = (const float*)d_in[13];
    const float* w_g2    = (const float*)d_in[14];
    const float* b_g2    = (const float*)d_in[15];
    float* out = (float*)d_out;

    char* ws = (char*)d_ws;
    size_t off = 0;
    auto alloc = [&](size_t bytes) -> char* {
        char* p = ws + off;
        off += (bytes + 255) & ~(size_t)255;
        return p;
    };
    float*          h    = (float*)alloc((size_t)NN * HD * 4);               // 25.6 MB
    unsigned short* hb   = (unsigned short*)alloc((size_t)NN * HD * 2);      // 12.8 MB
    unsigned short* t    = (unsigned short*)alloc((size_t)(NN + 1) * HD * 2);// 12.8 MB (+sentinel row)
    unsigned short* aggb = (unsigned short*)alloc((size_t)NN * FD * 2);      // 12.8 MB
    float*          T    = (float*)alloc((size_t)NB * FD * 4);               // 0.5 MB
    uint2*          Tpb  = (uint2*)alloc((size_t)NB * 64 * 8);               // 0.5 MB
    int*            deg  = (int*)alloc((size_t)NN * 4);                      // 0.2 MB
    unsigned int*   emll = (unsigned int*)alloc((size_t)NN * ELLS * 4);      // 16 MB
    unsigned short* welT = (unsigned short*)alloc((size_t)HD * FD * 2);
    unsigned short* wnmT = (unsigned short*)alloc((size_t)FD * HD * 2);
    unsigned short* wg1T = (unsigned short*)alloc((size_t)64 * HD * 2);
    unsigned short* tv   = (unsigned short*)alloc((size_t)100 * FD * 2);
    if (off > ws_size) return;  // workspace too small -> fail visibly, no OOB

    hipMemsetAsync(deg, 0, (size_t)NN * 4, stream);
    hipMemsetAsync(out, 0, (size_t)NGR * 4, stream);
    hipMemsetAsync(t + (size_t)NN * HD, 0, HD * 2, stream);   // sentinel row = 0

    k_table<<<NB, 128, 0, stream>>>(w_e1, b_e1, w_e2, b_e2, T);
    k_tpair<<<((NB - 1) * 64 + 255) / 256, 256, 0, stream>>>(T, Tpb);
    k_prepw<<<(40960 + 255) / 256, 256, 0, stream>>>(w_el, w_nm, w_g1, welT, wnmT, wg1T);
    k_tv<<<100, 128, 0, stream>>>(emb, w_el, tv);
    k_embed<<<(NN * (HD / 4) + 255) / 256, 256, 0, stream>>>(charges, emb, tv, h, t);
    k_edgeprep<<<(NE + 255) / 256, 256, 0, stream>>>(eidx, coords, deg, emll);
    k_ellpad<<<(NN + 255) / 256, 256, 0, stream>>>(deg, emll);

    // iteration 1: t1 came from k_embed (vocab trick)
    k_agg<<<NN / 4, 256, 0, stream>>>(t, Tpb, deg, emll, aggb);
    k_gemm_mfma<<<(NN + 127) / 128, 512, 0, stream>>>(aggb, wnmT, h, b_nm, h, hb, NN);
    // iteration 2
    k_gemm_mfma<<<(NN + 127) / 128, 512, 0, stream>>>(hb, welT, nullptr, nullptr, nullptr, t, NN);
    k_agg<<<NN / 4, 256, 0, stream>>>(t, Tpb, deg, emll, aggb);
    k_gemm_mfma<<<(NN + 127) / 128, 512, 0, stream>>>(aggb, wnmT, h, b_nm, nullptr, hb, NN);

    k_readout<<<(NN + 127) / 128, 512, 0, stream>>>(hb, batch, wg1T, b_g1, w_g2, b_g2, out);
}